// Round 1
// baseline (1061.092 us; speedup 1.0000x reference)
//
#include <hip/hip_runtime.h>
#include <hip/hip_bf16.h>

#define B_ 16
#define N_ 4096
#define S_ 1024
#define K_ 32
#define D_ 64
#define M_ (B_*S_*K_)            // 524288 rows
#define EPS_ 1e-5f

#define OUT_NRM  (B_*S_*3)       // 49152
#define OUT_FEAT (2*B_*S_*3)     // 98304
#define OUT_FPS  (OUT_FEAT + B_*S_*128)  // 2195456

// stats layout (float index): S1=0 Q1=64 S2=128 Q2=192 S3=256(128) Q3=384(128)
//                             a1=512 s1=576 a2=640 s2=704 a3=768(128) s3=896(128)

__global__ void zero_stats_kernel(float* __restrict__ stats){
  int t = blockIdx.x*256 + threadIdx.x;
  if (t < 512) stats[t] = 0.f;
}

__global__ void meta_kernel(const float* __restrict__ xyz, const float* __restrict__ nrm,
                            const int* __restrict__ fps, float* __restrict__ out){
  int t = blockIdx.x*256 + threadIdx.x;
  if (t >= B_*S_) return;
  int b = t >> 10;
  int n = fps[t];
  const float* xp = xyz + ((size_t)b*N_ + n)*3;
  out[t*3+0] = xp[0]; out[t*3+1] = xp[1]; out[t*3+2] = xp[2];
  const float* pp = nrm + ((size_t)b*N_ + n)*3;
  out[OUT_NRM + t*3+0] = pp[0]; out[OUT_NRM + t*3+1] = pp[1]; out[OUT_NRM + t*3+2] = pp[2];
  out[OUT_FPS + t] = (float)n;   // harness reads whole buffer as f32
}

// ---------------- KNN: one wave per query, 4 queries/block ----------------
__global__ __launch_bounds__(256) void knn_kernel(const float* __restrict__ xyz,
                                                  const int* __restrict__ fps,
                                                  int* __restrict__ idxout){
  __shared__ float dist[4][64*65];   // stride 65 -> conflict-free strided rescan
  const int w = threadIdx.x >> 6;
  const int l = threadIdx.x & 63;
  const int q = blockIdx.x*4 + w;        // 0..16383
  const int b = q >> 10;
  const float* xb = xyz + (size_t)b*N_*3;
  const int nq = fps[q];
  const float qx = xb[nq*3+0], qy = xb[nq*3+1], qz = xb[nq*3+2];
  const float qq = __fadd_rn(__fadd_rn(__fmul_rn(qx,qx), __fmul_rn(qy,qy)), __fmul_rn(qz,qz));
  float* dw = dist[w];
  float vmin = 3.0e38f; int imin = 0x7FFFFFFF;
  for (int i = 0; i < 64; i++){
    int n = i*64 + l;
    float px = xb[n*3+0], py = xb[n*3+1], pz = xb[n*3+2];
    float pp = __fadd_rn(__fadd_rn(__fmul_rn(px,px), __fmul_rn(py,py)), __fmul_rn(pz,pz));
    float dt = __fadd_rn(__fadd_rn(__fmul_rn(qx,px), __fmul_rn(qy,py)), __fmul_rn(qz,pz));
    float d  = __fsub_rn(__fadd_rn(qq,pp), __fmul_rn(2.f,dt));
    dw[i*65 + l] = d;
    if (d < vmin || (d == vmin && n < imin)) { vmin = d; imin = n; }
  }
  __syncthreads();
  const int obase = q*K_;
  for (int kk = 0; kk < K_; kk++){
    float v = vmin; int ix = imin;
    #pragma unroll
    for (int off = 32; off > 0; off >>= 1){
      float ov = __shfl_down(v, off);
      int   oi = __shfl_down(ix, off);
      if (ov < v || (ov == v && oi < ix)) { v = ov; ix = oi; }
    }
    v = __shfl(v, 0); ix = __shfl(ix, 0);
    if (l == 0) idxout[obase + kk] = ix;
    const int ol = ix & 63, os = ix >> 6;
    if (l == ol) dw[os*65 + l] = 3.0e38f;
    __syncthreads();
    // cooperative rescan of owner's 64 slots (stride-65 -> conflict-free)
    float rv = dw[l*65 + ol];
    int   rn = l*64 + ol;
    #pragma unroll
    for (int off = 32; off > 0; off >>= 1){
      float ov = __shfl_down(rv, off);
      int   oi = __shfl_down(rn, off);
      if (ov < rv || (ov == rv && oi < rn)) { rv = ov; rn = oi; }
    }
    rv = __shfl(rv, 0); rn = __shfl(rn, 0);
    if (l == ol) { vmin = rv; imin = rn; }
    __syncthreads();
  }
}

// ---------------- conv1: gather(points) -> y1(bf16) + stats ----------------
__global__ __launch_bounds__(256) void conv1_kernel(const float* __restrict__ points,
    const int* __restrict__ idx, const float* __restrict__ W, const float* __restrict__ bias,
    __hip_bfloat16* __restrict__ yout, float* __restrict__ stats){
  __shared__ float Xs[128*64];
  __shared__ int ridx[128];
  __shared__ float sred[512];
  const int t = threadIdx.x, w = t >> 6, l = t & 63;
  const int m0 = blockIdx.x * 128;
  if (t < 128) ridx[t] = idx[m0 + t];
  __syncthreads();
  const int b = m0 >> 15;                      // S*K = 32768 rows per batch
  const float4* pb = (const float4*)(points + (size_t)b*N_*D_);
  #pragma unroll
  for (int i = 0; i < 8; i++){
    int f4 = i*256 + t;                        // 0..2047 float4 slots
    int r = f4 >> 4, c4 = f4 & 15;
    float4 v = pb[(size_t)ridx[r]*16 + c4];
    ((float4*)Xs)[f4] = v;
  }
  float wreg[64];
  {
    const float4* Wv = (const float4*)(W + (size_t)l*64);
    #pragma unroll
    for (int j = 0; j < 16; j++){
      float4 wv = Wv[j];
      wreg[4*j+0]=wv.x; wreg[4*j+1]=wv.y; wreg[4*j+2]=wv.z; wreg[4*j+3]=wv.w;
    }
  }
  const float bo = bias[l];
  __syncthreads();
  float sA = 0.f, sQ = 0.f;
  const int r0 = w*32;
  for (int r = r0; r < r0+32; r += 2){
    const float4* x0 = (const float4*)(Xs + r*64);
    const float4* x1 = (const float4*)(Xs + (r+1)*64);
    float a0 = bo, a1 = bo;
    #pragma unroll
    for (int j = 0; j < 16; j++){
      float4 v0 = x0[j], v1 = x1[j];
      a0 += v0.x*wreg[4*j] + v0.y*wreg[4*j+1] + v0.z*wreg[4*j+2] + v0.w*wreg[4*j+3];
      a1 += v1.x*wreg[4*j] + v1.y*wreg[4*j+1] + v1.z*wreg[4*j+2] + v1.w*wreg[4*j+3];
    }
    yout[(size_t)(m0+r)*64 + l]   = __float2bfloat16(a0);
    yout[(size_t)(m0+r+1)*64 + l] = __float2bfloat16(a1);
    sA += a0 + a1; sQ += a0*a0 + a1*a1;
  }
  sred[w*64 + l] = sA; sred[256 + w*64 + l] = sQ;
  __syncthreads();
  if (t < 64){
    unsafeAtomicAdd(&stats[0 + t], sred[t] + sred[64+t] + sred[128+t] + sred[192+t]);
  } else if (t < 128){
    int c = t - 64;
    unsafeAtomicAdd(&stats[64 + c], sred[256+c] + sred[320+c] + sred[384+c] + sred[448+c]);
  }
}

// ---------------- conv2: relu(a*y1+s) -> y2(bf16) + stats ----------------
__global__ __launch_bounds__(256) void conv2_kernel(const __hip_bfloat16* __restrict__ yin,
    const float* __restrict__ W, const float* __restrict__ bias, const float* __restrict__ aff,
    __hip_bfloat16* __restrict__ yout, float* __restrict__ stats){
  __shared__ float Xs[128*64];
  __shared__ float affA[64], affB[64];
  __shared__ float sred[512];
  const int t = threadIdx.x, w = t >> 6, l = t & 63;
  const int m0 = blockIdx.x * 128;
  if (t < 64) affA[t] = aff[t];
  else if (t < 128) affB[t-64] = aff[t];       // aff[64..127] = shift
  __syncthreads();
  const uint4* yv = (const uint4*)(yin + (size_t)m0*64);
  #pragma unroll
  for (int i = 0; i < 4; i++){
    int f8 = i*256 + t;                        // 0..1023, 8 bf16 each
    uint4 u = yv[f8];
    int r = f8 >> 3, c8 = (f8 & 7)*8;
    unsigned int ua[4] = {u.x, u.y, u.z, u.w};
    float tmp[8];
    #pragma unroll
    for (int j = 0; j < 4; j++){
      float lo = __uint_as_float(ua[j] << 16);
      float hi = __uint_as_float(ua[j] & 0xFFFF0000u);
      int c = c8 + 2*j;
      tmp[2*j]   = fmaxf(0.f, lo*affA[c]   + affB[c]);
      tmp[2*j+1] = fmaxf(0.f, hi*affA[c+1] + affB[c+1]);
    }
    float4* xd = (float4*)(Xs + r*64 + c8);
    float4 f0, f1;
    f0.x=tmp[0]; f0.y=tmp[1]; f0.z=tmp[2]; f0.w=tmp[3];
    f1.x=tmp[4]; f1.y=tmp[5]; f1.z=tmp[6]; f1.w=tmp[7];
    xd[0] = f0; xd[1] = f1;
  }
  float wreg[64];
  {
    const float4* Wv = (const float4*)(W + (size_t)l*64);
    #pragma unroll
    for (int j = 0; j < 16; j++){
      float4 wv = Wv[j];
      wreg[4*j+0]=wv.x; wreg[4*j+1]=wv.y; wreg[4*j+2]=wv.z; wreg[4*j+3]=wv.w;
    }
  }
  const float bo = bias[l];
  __syncthreads();
  float sA = 0.f, sQ = 0.f;
  const int r0 = w*32;
  for (int r = r0; r < r0+32; r += 2){
    const float4* x0 = (const float4*)(Xs + r*64);
    const float4* x1 = (const float4*)(Xs + (r+1)*64);
    float a0 = bo, a1 = bo;
    #pragma unroll
    for (int j = 0; j < 16; j++){
      float4 v0 = x0[j], v1 = x1[j];
      a0 += v0.x*wreg[4*j] + v0.y*wreg[4*j+1] + v0.z*wreg[4*j+2] + v0.w*wreg[4*j+3];
      a1 += v1.x*wreg[4*j] + v1.y*wreg[4*j+1] + v1.z*wreg[4*j+2] + v1.w*wreg[4*j+3];
    }
    yout[(size_t)(m0+r)*64 + l]   = __float2bfloat16(a0);
    yout[(size_t)(m0+r+1)*64 + l] = __float2bfloat16(a1);
    sA += a0 + a1; sQ += a0*a0 + a1*a1;
  }
  sred[w*64 + l] = sA; sred[256 + w*64 + l] = sQ;
  __syncthreads();
  if (t < 64){
    unsafeAtomicAdd(&stats[128 + t], sred[t] + sred[64+t] + sred[128+t] + sred[192+t]);
  } else if (t < 128){
    int c = t - 64;
    unsafeAtomicAdd(&stats[192 + c], sred[256+c] + sred[320+c] + sred[384+c] + sred[448+c]);
  }
}

// -------- conv3: relu(a*y2+s) -> stats + fused K-max/min (no y3 store) --------
__global__ __launch_bounds__(256) void conv3_kernel(const __hip_bfloat16* __restrict__ yin,
    const float* __restrict__ W, const float* __restrict__ bias, const float* __restrict__ aff,
    float* __restrict__ ymax, float* __restrict__ ymin, float* __restrict__ stats){
  __shared__ float Xs[128*64];
  __shared__ float affA[64], affB[64];
  __shared__ float sred[1024];
  const int t = threadIdx.x, w = t >> 6, l = t & 63;
  const int m0 = blockIdx.x * 128;
  if (t < 64) affA[t] = aff[t];
  else if (t < 128) affB[t-64] = aff[t];
  __syncthreads();
  const uint4* yv = (const uint4*)(yin + (size_t)m0*64);
  #pragma unroll
  for (int i = 0; i < 4; i++){
    int f8 = i*256 + t;
    uint4 u = yv[f8];
    int r = f8 >> 3, c8 = (f8 & 7)*8;
    unsigned int ua[4] = {u.x, u.y, u.z, u.w};
    float tmp[8];
    #pragma unroll
    for (int j = 0; j < 4; j++){
      float lo = __uint_as_float(ua[j] << 16);
      float hi = __uint_as_float(ua[j] & 0xFFFF0000u);
      int c = c8 + 2*j;
      tmp[2*j]   = fmaxf(0.f, lo*affA[c]   + affB[c]);
      tmp[2*j+1] = fmaxf(0.f, hi*affA[c+1] + affB[c+1]);
    }
    float4* xd = (float4*)(Xs + r*64 + c8);
    float4 f0, f1;
    f0.x=tmp[0]; f0.y=tmp[1]; f0.z=tmp[2]; f0.w=tmp[3];
    f1.x=tmp[4]; f1.y=tmp[5]; f1.z=tmp[6]; f1.w=tmp[7];
    xd[0] = f0; xd[1] = f1;
  }
  float wA[64], wB[64];
  {
    const float4* WvA = (const float4*)(W + (size_t)l*64);
    const float4* WvB = (const float4*)(W + (size_t)(l+64)*64);
    #pragma unroll
    for (int j = 0; j < 16; j++){
      float4 a = WvA[j], b = WvB[j];
      wA[4*j+0]=a.x; wA[4*j+1]=a.y; wA[4*j+2]=a.z; wA[4*j+3]=a.w;
      wB[4*j+0]=b.x; wB[4*j+1]=b.y; wB[4*j+2]=b.z; wB[4*j+3]=b.w;
    }
  }
  const float bo0 = bias[l], bo1 = bias[l+64];
  __syncthreads();
  float sA0=0.f, sQ0=0.f, sA1=0.f, sQ1=0.f;
  float g0=-3.0e38f, g1=-3.0e38f, n0=3.0e38f, n1=3.0e38f;
  const int r0 = w*32;                       // one (b,s) group of K=32 rows per wave
  for (int r = r0; r < r0+32; r++){
    const float4* xv = (const float4*)(Xs + r*64);
    float a0 = bo0, a1 = bo1;
    #pragma unroll
    for (int j = 0; j < 16; j++){
      float4 v = xv[j];
      a0 += v.x*wA[4*j] + v.y*wA[4*j+1] + v.z*wA[4*j+2] + v.w*wA[4*j+3];
      a1 += v.x*wB[4*j] + v.y*wB[4*j+1] + v.z*wB[4*j+2] + v.w*wB[4*j+3];
    }
    sA0 += a0; sQ0 += a0*a0; sA1 += a1; sQ1 += a1*a1;
    g0 = fmaxf(g0, a0); n0 = fminf(n0, a0);
    g1 = fmaxf(g1, a1); n1 = fminf(n1, a1);
  }
  const int g = (m0 >> 5) + w;               // group = b*S + s
  ymax[(size_t)g*128 + l]      = g0;
  ymax[(size_t)g*128 + 64 + l] = g1;
  ymin[(size_t)g*128 + l]      = n0;
  ymin[(size_t)g*128 + 64 + l] = n1;
  sred[w*128 + l] = sA0; sred[w*128 + 64 + l] = sA1;
  sred[512 + w*128 + l] = sQ0; sred[512 + w*128 + 64 + l] = sQ1;
  __syncthreads();
  if (t < 128){
    unsafeAtomicAdd(&stats[256 + t], sred[t] + sred[128+t] + sred[256+t] + sred[384+t]);
  } else {
    int c = t - 128;
    unsafeAtomicAdd(&stats[384 + c], sred[512+c] + sred[640+c] + sred[768+c] + sred[896+c]);
  }
}

__global__ void bnparam_kernel(const float* __restrict__ stats, const float* __restrict__ g,
                               const float* __restrict__ bt, float* __restrict__ outAS,
                               int sOff, int qOff, int C){
  int c = threadIdx.x;
  if (c >= C) return;
  const float inv = 1.f/(float)M_;
  float mean = stats[sOff + c] * inv;
  float var  = stats[qOff + c] * inv - mean*mean;
  float a = g[c] * rsqrtf(var + EPS_);
  outAS[c] = a;
  outAS[C + c] = bt[c] - mean*a;
}

__global__ void final_kernel(const float* __restrict__ ymax, const float* __restrict__ ymin,
                             const float* __restrict__ stats, float* __restrict__ out){
  int t = blockIdx.x*256 + threadIdx.x;     // 0..2097151 = (b*S+s)*128 + o
  int o = t & 127;
  float a = stats[768 + o], s = stats[896 + o];
  float v = (a >= 0.f) ? ymax[t] : ymin[t]; // max_k relu(a*y+s) = relu(a*max_k y + s) for a>=0
  out[OUT_FEAT + t] = fmaxf(0.f, a*v + s);
}

extern "C" void kernel_launch(void* const* d_in, const int* in_sizes, int n_in,
                              void* d_out, int out_size, void* d_ws, size_t ws_size,
                              hipStream_t stream) {
  const float* xyz = (const float*)d_in[0];
  const float* nrm = (const float*)d_in[1];
  const float* pts = (const float*)d_in[2];
  const int*   fps = (const int*)d_in[3];
  const float* w0  = (const float*)d_in[4];
  const float* b0  = (const float*)d_in[5];
  const float* g0  = (const float*)d_in[6];
  const float* bt0 = (const float*)d_in[7];
  const float* w1  = (const float*)d_in[8];
  const float* b1  = (const float*)d_in[9];
  const float* g1  = (const float*)d_in[10];
  const float* bt1 = (const float*)d_in[11];
  const float* w2  = (const float*)d_in[12];
  const float* b2  = (const float*)d_in[13];
  const float* g2  = (const float*)d_in[14];
  const float* bt2 = (const float*)d_in[15];
  float* out = (float*)d_out;

  char* ws = (char*)d_ws;
  float* stats = (float*)ws;                                  // 4 KB
  int*   idxb  = (int*)(ws + 4096);                           // 2 MB
  float* ymax  = (float*)(ws + 2101248);                      // 8 MB
  float* ymin  = (float*)(ws + 10489856);                     // 8 MB
  __hip_bfloat16* y1 = (__hip_bfloat16*)(ws + 18878464);      // 64 MB
  __hip_bfloat16* y2 = (__hip_bfloat16*)(ws + 85987328);      // 64 MB (ends 153096192)

  zero_stats_kernel<<<2, 256, 0, stream>>>(stats);
  meta_kernel<<<64, 256, 0, stream>>>(xyz, nrm, fps, out);
  knn_kernel<<<4096, 256, 0, stream>>>(xyz, fps, idxb);
  conv1_kernel<<<4096, 256, 0, stream>>>(pts, idxb, w0, b0, y1, stats);
  bnparam_kernel<<<1, 64, 0, stream>>>(stats, g0, bt0, stats + 512, 0, 64, 64);
  conv2_kernel<<<4096, 256, 0, stream>>>(y1, w1, b1, stats + 512, y2, stats);
  bnparam_kernel<<<1, 64, 0, stream>>>(stats, g1, bt1, stats + 640, 128, 192, 64);
  conv3_kernel<<<4096, 256, 0, stream>>>(y2, w2, b2, stats + 640, ymax, ymin, stats);
  bnparam_kernel<<<1, 128, 0, stream>>>(stats, g2, bt2, stats + 768, 256, 384, 128);
  final_kernel<<<8192, 256, 0, stream>>>(ymax, ymin, stats, out);
}

// Round 2
// 677.937 us; speedup vs baseline: 1.5652x; 1.5652x over previous
//
#include <hip/hip_runtime.h>
#include <hip/hip_bf16.h>

#define B_ 16
#define N_ 4096
#define S_ 1024
#define K_ 32
#define D_ 64
#define M_ (B_*S_*K_)            // 524288 rows
#define EPS_ 1e-5f

#define OUT_NRM  (B_*S_*3)       // 49152
#define OUT_FEAT (2*B_*S_*3)     // 98304
#define OUT_FPS  (OUT_FEAT + B_*S_*128)  // 2195456

// stats layout (float index): S1=0 Q1=64 S2=128 Q2=192 S3=256(128) Q3=384(128)
//                             a1=512 s1=576 a2=640 s2=704 a3=768(128) s3=896(128)

__global__ void zero_stats_kernel(float* __restrict__ stats){
  int t = blockIdx.x*256 + threadIdx.x;
  if (t < 512) stats[t] = 0.f;
}

__global__ void meta_kernel(const float* __restrict__ xyz, const float* __restrict__ nrm,
                            const int* __restrict__ fps, float* __restrict__ out){
  int t = blockIdx.x*256 + threadIdx.x;
  if (t >= B_*S_) return;
  int b = t >> 10;
  int n = fps[t];
  const float* xp = xyz + ((size_t)b*N_ + n)*3;
  out[t*3+0] = xp[0]; out[t*3+1] = xp[1]; out[t*3+2] = xp[2];
  const float* pp = nrm + ((size_t)b*N_ + n)*3;
  out[OUT_NRM + t*3+0] = pp[0]; out[OUT_NRM + t*3+1] = pp[1]; out[OUT_NRM + t*3+2] = pp[2];
  out[OUT_FPS + t] = (float)n;   // harness reads whole buffer as f32
}

// pack [x,y,z,||p||^2] with rounding identical to the previous (passing) kernel
__global__ void prepack_kernel(const float* __restrict__ xyz, float4* __restrict__ packed){
  int t = blockIdx.x*256 + threadIdx.x;
  if (t >= B_*N_) return;
  float x = xyz[t*3+0], y = xyz[t*3+1], z = xyz[t*3+2];
  float pp = __fadd_rn(__fadd_rn(__fmul_rn(x,x), __fmul_rn(y,y)), __fmul_rn(z,z));
  packed[t] = make_float4(x, y, z, pp);
}

// ---------------- KNN: one wave per query, barrier-free, register-resident ----------------
__global__ __launch_bounds__(256, 3) void knn_kernel(const float4* __restrict__ packed,
                                                     const int* __restrict__ fps,
                                                     int* __restrict__ idxout){
  __shared__ unsigned skey[4][64];   // per-wave compaction buffers (no cross-wave use)
  __shared__ int      sidx[4][64];
  const int w = threadIdx.x >> 6;
  const int l = threadIdx.x & 63;
  const int q = blockIdx.x*4 + w;        // 0..16383
  const int b = q >> 10;
  const float4* pb = packed + (size_t)b*N_;
  const int nq = fps[q];
  const float4 qp = pb[nq];
  const float qx = qp.x, qy = qp.y, qz = qp.z, qq = qp.w;

  // distances -> sortable uint keys, per-lane min
  unsigned key[64];
  unsigned minkey = 0xFFFFFFFFu;
  #pragma unroll
  for (int i = 0; i < 64; i++){
    float4 p = pb[i*64 + l];
    float dt = __fadd_rn(__fadd_rn(__fmul_rn(qx,p.x), __fmul_rn(qy,p.y)), __fmul_rn(qz,p.z));
    float d  = __fsub_rn(__fadd_rn(qq,p.w), __fmul_rn(2.f,dt));
    unsigned u = __float_as_uint(d);
    u ^= (unsigned)(((int)u >> 31)) | 0x80000000u;   // float -> order-preserving uint
    key[i] = u;
    minkey = min(minkey, u);
  }

  // bitonic sort the 64 lane-minima; rank-31 value is an upper bound on global 32nd-smallest
  {
    unsigned v = minkey;
    #pragma unroll
    for (int k = 2; k <= 64; k <<= 1){
      #pragma unroll
      for (int j = k >> 1; j > 0; j >>= 1){
        unsigned o = (unsigned)__shfl_xor((int)v, j);
        bool keepmin = (((l & k) == 0)) ^ ((l & j) != 0);
        unsigned mn = min(v, o), mx = max(v, o);
        v = keepmin ? mn : mx;
      }
    }
    minkey = v;
  }
  const unsigned T = (unsigned)__shfl((int)minkey, 31);

  // count survivors (key <= T), prefix-scan for compaction offsets
  int c = 0;
  #pragma unroll
  for (int i = 0; i < 64; i++) c += (key[i] <= T) ? 1 : 0;
  int inc = c;
  #pragma unroll
  for (int off = 1; off < 64; off <<= 1){
    int t2 = __shfl_up(inc, off);
    if (l >= off) inc += t2;
  }
  const int excl = inc - c;
  const int total = __shfl(inc, 63);   // >= 32 guaranteed

  const size_t obase = (size_t)q * K_;
  if (total <= 64){
    // compact survivors into per-wave LDS (same-wave, no barrier needed)
    int off = excl;
    #pragma unroll
    for (int i = 0; i < 64; i++){
      if (key[i] <= T){
        skey[w][off] = key[i];
        sidx[w][off] = i*64 + l;
        off++;
      }
    }
    unsigned mykey = 0xFFFFFFFFu, myidx = 0xFFFFFFFFu;
    if (l < total){ mykey = skey[w][l]; myidx = (unsigned)sidx[w][l]; }
    unsigned long long sk = ((unsigned long long)mykey << 32) | (unsigned long long)myidx;
    // bitonic sort 64 (key,idx) pairs ascending -> lanes 0..31 hold exact top-32 (ref tie-break)
    #pragma unroll
    for (int k = 2; k <= 64; k <<= 1){
      #pragma unroll
      for (int j = k >> 1; j > 0; j >>= 1){
        unsigned long long o = __shfl_xor(sk, j);
        bool keepmin = (((l & k) == 0)) ^ ((l & j) != 0);
        unsigned long long mn = (sk < o) ? sk : o;
        unsigned long long mx = (sk < o) ? o : sk;
        sk = keepmin ? mn : mx;
      }
    }
    if (l < 32) idxout[obase + l] = (int)(unsigned)(sk & 0xFFFFFFFFull);
  } else {
    // rare exact fallback: bisection on 44-bit (key, idx) lexicographic domain
    unsigned long long lo = 0, hi = (1ull << 44) - 1;
    for (int it = 0; it < 44; ++it){
      unsigned long long mid = (lo + hi) >> 1;
      unsigned midk = (unsigned)(mid >> 12);
      unsigned midi = (unsigned)(mid & 0xFFFull);
      int cc = 0;
      #pragma unroll
      for (int i = 0; i < 64; i++){
        unsigned n = (unsigned)(i*64 + l);
        cc += (key[i] < midk || (key[i] == midk && n <= midi)) ? 1 : 0;
      }
      #pragma unroll
      for (int o2 = 32; o2 > 0; o2 >>= 1) cc += __shfl_xor(cc, o2);
      if (cc >= 32) hi = mid; else lo = mid + 1;
    }
    const unsigned Ck = (unsigned)(lo >> 12);
    const unsigned Ci = (unsigned)(lo & 0xFFFull);
    int c2 = 0;
    #pragma unroll
    for (int i = 0; i < 64; i++){
      unsigned n = (unsigned)(i*64 + l);
      c2 += (key[i] < Ck || (key[i] == Ck && n <= Ci)) ? 1 : 0;
    }
    int inc2 = c2;
    #pragma unroll
    for (int off = 1; off < 64; off <<= 1){
      int t2 = __shfl_up(inc2, off);
      if (l >= off) inc2 += t2;
    }
    int off3 = inc2 - c2;
    #pragma unroll
    for (int i = 0; i < 64; i++){
      unsigned n = (unsigned)(i*64 + l);
      if (key[i] < Ck || (key[i] == Ck && n <= Ci)){
        sidx[w][off3] = i*64 + l;
        off3++;
      }
    }
    if (l < 32) idxout[obase + l] = sidx[w][l];   // exactly 32 survivors
  }
}

// ---------------- conv1: gather(points) -> y1(bf16) + stats ----------------
__global__ __launch_bounds__(256) void conv1_kernel(const float* __restrict__ points,
    const int* __restrict__ idx, const float* __restrict__ W, const float* __restrict__ bias,
    __hip_bfloat16* __restrict__ yout, float* __restrict__ stats){
  __shared__ float Xs[128*64];
  __shared__ int ridx[128];
  __shared__ float sred[512];
  const int t = threadIdx.x, w = t >> 6, l = t & 63;
  const int m0 = blockIdx.x * 128;
  if (t < 128) ridx[t] = idx[m0 + t];
  __syncthreads();
  const int b = m0 >> 15;                      // S*K = 32768 rows per batch
  const float4* pb = (const float4*)(points + (size_t)b*N_*D_);
  #pragma unroll
  for (int i = 0; i < 8; i++){
    int f4 = i*256 + t;                        // 0..2047 float4 slots
    int r = f4 >> 4, c4 = f4 & 15;
    float4 v = pb[(size_t)ridx[r]*16 + c4];
    ((float4*)Xs)[f4] = v;
  }
  float wreg[64];
  {
    const float4* Wv = (const float4*)(W + (size_t)l*64);
    #pragma unroll
    for (int j = 0; j < 16; j++){
      float4 wv = Wv[j];
      wreg[4*j+0]=wv.x; wreg[4*j+1]=wv.y; wreg[4*j+2]=wv.z; wreg[4*j+3]=wv.w;
    }
  }
  const float bo = bias[l];
  __syncthreads();
  float sA = 0.f, sQ = 0.f;
  const int r0 = w*32;
  for (int r = r0; r < r0+32; r += 2){
    const float4* x0 = (const float4*)(Xs + r*64);
    const float4* x1 = (const float4*)(Xs + (r+1)*64);
    float a0 = bo, a1 = bo;
    #pragma unroll
    for (int j = 0; j < 16; j++){
      float4 v0 = x0[j], v1 = x1[j];
      a0 += v0.x*wreg[4*j] + v0.y*wreg[4*j+1] + v0.z*wreg[4*j+2] + v0.w*wreg[4*j+3];
      a1 += v1.x*wreg[4*j] + v1.y*wreg[4*j+1] + v1.z*wreg[4*j+2] + v1.w*wreg[4*j+3];
    }
    yout[(size_t)(m0+r)*64 + l]   = __float2bfloat16(a0);
    yout[(size_t)(m0+r+1)*64 + l] = __float2bfloat16(a1);
    sA += a0 + a1; sQ += a0*a0 + a1*a1;
  }
  sred[w*64 + l] = sA; sred[256 + w*64 + l] = sQ;
  __syncthreads();
  if (t < 64){
    unsafeAtomicAdd(&stats[0 + t], sred[t] + sred[64+t] + sred[128+t] + sred[192+t]);
  } else if (t < 128){
    int c = t - 64;
    unsafeAtomicAdd(&stats[64 + c], sred[256+c] + sred[320+c] + sred[384+c] + sred[448+c]);
  }
}

// ---------------- conv2: relu(a*y1+s) -> y2(bf16) + stats ----------------
__global__ __launch_bounds__(256) void conv2_kernel(const __hip_bfloat16* __restrict__ yin,
    const float* __restrict__ W, const float* __restrict__ bias, const float* __restrict__ aff,
    __hip_bfloat16* __restrict__ yout, float* __restrict__ stats){
  __shared__ float Xs[128*64];
  __shared__ float affA[64], affB[64];
  __shared__ float sred[512];
  const int t = threadIdx.x, w = t >> 6, l = t & 63;
  const int m0 = blockIdx.x * 128;
  if (t < 64) affA[t] = aff[t];
  else if (t < 128) affB[t-64] = aff[t];       // aff[64..127] = shift
  __syncthreads();
  const uint4* yv = (const uint4*)(yin + (size_t)m0*64);
  #pragma unroll
  for (int i = 0; i < 4; i++){
    int f8 = i*256 + t;                        // 0..1023, 8 bf16 each
    uint4 u = yv[f8];
    int r = f8 >> 3, c8 = (f8 & 7)*8;
    unsigned int ua[4] = {u.x, u.y, u.z, u.w};
    float tmp[8];
    #pragma unroll
    for (int j = 0; j < 4; j++){
      float lo = __uint_as_float(ua[j] << 16);
      float hi = __uint_as_float(ua[j] & 0xFFFF0000u);
      int c = c8 + 2*j;
      tmp[2*j]   = fmaxf(0.f, lo*affA[c]   + affB[c]);
      tmp[2*j+1] = fmaxf(0.f, hi*affA[c+1] + affB[c+1]);
    }
    float4* xd = (float4*)(Xs + r*64 + c8);
    float4 f0, f1;
    f0.x=tmp[0]; f0.y=tmp[1]; f0.z=tmp[2]; f0.w=tmp[3];
    f1.x=tmp[4]; f1.y=tmp[5]; f1.z=tmp[6]; f1.w=tmp[7];
    xd[0] = f0; xd[1] = f1;
  }
  float wreg[64];
  {
    const float4* Wv = (const float4*)(W + (size_t)l*64);
    #pragma unroll
    for (int j = 0; j < 16; j++){
      float4 wv = Wv[j];
      wreg[4*j+0]=wv.x; wreg[4*j+1]=wv.y; wreg[4*j+2]=wv.z; wreg[4*j+3]=wv.w;
    }
  }
  const float bo = bias[l];
  __syncthreads();
  float sA = 0.f, sQ = 0.f;
  const int r0 = w*32;
  for (int r = r0; r < r0+32; r += 2){
    const float4* x0 = (const float4*)(Xs + r*64);
    const float4* x1 = (const float4*)(Xs + (r+1)*64);
    float a0 = bo, a1 = bo;
    #pragma unroll
    for (int j = 0; j < 16; j++){
      float4 v0 = x0[j], v1 = x1[j];
      a0 += v0.x*wreg[4*j] + v0.y*wreg[4*j+1] + v0.z*wreg[4*j+2] + v0.w*wreg[4*j+3];
      a1 += v1.x*wreg[4*j] + v1.y*wreg[4*j+1] + v1.z*wreg[4*j+2] + v1.w*wreg[4*j+3];
    }
    yout[(size_t)(m0+r)*64 + l]   = __float2bfloat16(a0);
    yout[(size_t)(m0+r+1)*64 + l] = __float2bfloat16(a1);
    sA += a0 + a1; sQ += a0*a0 + a1*a1;
  }
  sred[w*64 + l] = sA; sred[256 + w*64 + l] = sQ;
  __syncthreads();
  if (t < 64){
    unsafeAtomicAdd(&stats[128 + t], sred[t] + sred[64+t] + sred[128+t] + sred[192+t]);
  } else if (t < 128){
    int c = t - 64;
    unsafeAtomicAdd(&stats[192 + c], sred[256+c] + sred[320+c] + sred[384+c] + sred[448+c]);
  }
}

// -------- conv3: relu(a*y2+s) -> stats + fused K-max/min (no y3 store) --------
__global__ __launch_bounds__(256) void conv3_kernel(const __hip_bfloat16* __restrict__ yin,
    const float* __restrict__ W, const float* __restrict__ bias, const float* __restrict__ aff,
    float* __restrict__ ymax, float* __restrict__ ymin, float* __restrict__ stats){
  __shared__ float Xs[128*64];
  __shared__ float affA[64], affB[64];
  __shared__ float sred[1024];
  const int t = threadIdx.x, w = t >> 6, l = t & 63;
  const int m0 = blockIdx.x * 128;
  if (t < 64) affA[t] = aff[t];
  else if (t < 128) affB[t-64] = aff[t];
  __syncthreads();
  const uint4* yv = (const uint4*)(yin + (size_t)m0*64);
  #pragma unroll
  for (int i = 0; i < 4; i++){
    int f8 = i*256 + t;
    uint4 u = yv[f8];
    int r = f8 >> 3, c8 = (f8 & 7)*8;
    unsigned int ua[4] = {u.x, u.y, u.z, u.w};
    float tmp[8];
    #pragma unroll
    for (int j = 0; j < 4; j++){
      float lo = __uint_as_float(ua[j] << 16);
      float hi = __uint_as_float(ua[j] & 0xFFFF0000u);
      int c = c8 + 2*j;
      tmp[2*j]   = fmaxf(0.f, lo*affA[c]   + affB[c]);
      tmp[2*j+1] = fmaxf(0.f, hi*affA[c+1] + affB[c+1]);
    }
    float4* xd = (float4*)(Xs + r*64 + c8);
    float4 f0, f1;
    f0.x=tmp[0]; f0.y=tmp[1]; f0.z=tmp[2]; f0.w=tmp[3];
    f1.x=tmp[4]; f1.y=tmp[5]; f1.z=tmp[6]; f1.w=tmp[7];
    xd[0] = f0; xd[1] = f1;
  }
  float wA[64], wB[64];
  {
    const float4* WvA = (const float4*)(W + (size_t)l*64);
    const float4* WvB = (const float4*)(W + (size_t)(l+64)*64);
    #pragma unroll
    for (int j = 0; j < 16; j++){
      float4 a = WvA[j], b = WvB[j];
      wA[4*j+0]=a.x; wA[4*j+1]=a.y; wA[4*j+2]=a.z; wA[4*j+3]=a.w;
      wB[4*j+0]=b.x; wB[4*j+1]=b.y; wB[4*j+2]=b.z; wB[4*j+3]=b.w;
    }
  }
  const float bo0 = bias[l], bo1 = bias[l+64];
  __syncthreads();
  float sA0=0.f, sQ0=0.f, sA1=0.f, sQ1=0.f;
  float g0=-3.0e38f, g1=-3.0e38f, n0=3.0e38f, n1=3.0e38f;
  const int r0 = w*32;                       // one (b,s) group of K=32 rows per wave
  for (int r = r0; r < r0+32; r++){
    const float4* xv = (const float4*)(Xs + r*64);
    float a0 = bo0, a1 = bo1;
    #pragma unroll
    for (int j = 0; j < 16; j++){
      float4 v = xv[j];
      a0 += v.x*wA[4*j] + v.y*wA[4*j+1] + v.z*wA[4*j+2] + v.w*wA[4*j+3];
      a1 += v.x*wB[4*j] + v.y*wB[4*j+1] + v.z*wB[4*j+2] + v.w*wB[4*j+3];
    }
    sA0 += a0; sQ0 += a0*a0; sA1 += a1; sQ1 += a1*a1;
    g0 = fmaxf(g0, a0); n0 = fminf(n0, a0);
    g1 = fmaxf(g1, a1); n1 = fminf(n1, a1);
  }
  const int g = (m0 >> 5) + w;               // group = b*S + s
  ymax[(size_t)g*128 + l]      = g0;
  ymax[(size_t)g*128 + 64 + l] = g1;
  ymin[(size_t)g*128 + l]      = n0;
  ymin[(size_t)g*128 + 64 + l] = n1;
  sred[w*128 + l] = sA0; sred[w*128 + 64 + l] = sA1;
  sred[512 + w*128 + l] = sQ0; sred[512 + w*128 + 64 + l] = sQ1;
  __syncthreads();
  if (t < 128){
    unsafeAtomicAdd(&stats[256 + t], sred[t] + sred[128+t] + sred[256+t] + sred[384+t]);
  } else {
    int c = t - 128;
    unsafeAtomicAdd(&stats[384 + c], sred[512+c] + sred[640+c] + sred[768+c] + sred[896+c]);
  }
}

__global__ void bnparam_kernel(const float* __restrict__ stats, const float* __restrict__ g,
                               const float* __restrict__ bt, float* __restrict__ outAS,
                               int sOff, int qOff, int C){
  int c = threadIdx.x;
  if (c >= C) return;
  const float inv = 1.f/(float)M_;
  float mean = stats[sOff + c] * inv;
  float var  = stats[qOff + c] * inv - mean*mean;
  float a = g[c] * rsqrtf(var + EPS_);
  outAS[c] = a;
  outAS[C + c] = bt[c] - mean*a;
}

__global__ void final_kernel(const float* __restrict__ ymax, const float* __restrict__ ymin,
                             const float* __restrict__ stats, float* __restrict__ out){
  int t = blockIdx.x*256 + threadIdx.x;     // 0..2097151 = (b*S+s)*128 + o
  int o = t & 127;
  float a = stats[768 + o], s = stats[896 + o];
  float v = (a >= 0.f) ? ymax[t] : ymin[t]; // max_k relu(a*y+s) = relu(a*max_k y + s) for a>=0
  out[OUT_FEAT + t] = fmaxf(0.f, a*v + s);
}

extern "C" void kernel_launch(void* const* d_in, const int* in_sizes, int n_in,
                              void* d_out, int out_size, void* d_ws, size_t ws_size,
                              hipStream_t stream) {
  const float* xyz = (const float*)d_in[0];
  const float* nrm = (const float*)d_in[1];
  const float* pts = (const float*)d_in[2];
  const int*   fps = (const int*)d_in[3];
  const float* w0  = (const float*)d_in[4];
  const float* b0  = (const float*)d_in[5];
  const float* g0  = (const float*)d_in[6];
  const float* bt0 = (const float*)d_in[7];
  const float* w1  = (const float*)d_in[8];
  const float* b1  = (const float*)d_in[9];
  const float* g1  = (const float*)d_in[10];
  const float* bt1 = (const float*)d_in[11];
  const float* w2  = (const float*)d_in[12];
  const float* b2  = (const float*)d_in[13];
  const float* g2  = (const float*)d_in[14];
  const float* bt2 = (const float*)d_in[15];
  float* out = (float*)d_out;

  char* ws = (char*)d_ws;
  float* stats = (float*)ws;                                  // 4 KB
  int*   idxb  = (int*)(ws + 4096);                           // 2 MB
  float* ymax  = (float*)(ws + 2101248);                      // 8 MB
  float* ymin  = (float*)(ws + 10489856);                     // 8 MB (written only in conv3)
  float4* packed = (float4*)(ws + 10489856);                  // 1 MB, overlaps ymin (used only before conv1)
  __hip_bfloat16* y1 = (__hip_bfloat16*)(ws + 18878464);      // 64 MB
  __hip_bfloat16* y2 = (__hip_bfloat16*)(ws + 85987328);      // 64 MB (ends 153096192)

  zero_stats_kernel<<<2, 256, 0, stream>>>(stats);
  meta_kernel<<<64, 256, 0, stream>>>(xyz, nrm, fps, out);
  prepack_kernel<<<256, 256, 0, stream>>>(xyz, packed);
  knn_kernel<<<4096, 256, 0, stream>>>(packed, fps, idxb);
  conv1_kernel<<<4096, 256, 0, stream>>>(pts, idxb, w0, b0, y1, stats);
  bnparam_kernel<<<1, 64, 0, stream>>>(stats, g0, bt0, stats + 512, 0, 64, 64);
  conv2_kernel<<<4096, 256, 0, stream>>>(y1, w1, b1, stats + 512, y2, stats);
  bnparam_kernel<<<1, 64, 0, stream>>>(stats, g1, bt1, stats + 640, 128, 192, 64);
  conv3_kernel<<<4096, 256, 0, stream>>>(y2, w2, b2, stats + 640, ymax, ymin, stats);
  bnparam_kernel<<<1, 128, 0, stream>>>(stats, g2, bt2, stats + 768, 256, 384, 128);
  final_kernel<<<8192, 256, 0, stream>>>(ymax, ymin, stats, out);
}

// Round 3
// 665.217 us; speedup vs baseline: 1.5951x; 1.0191x over previous
//
#include <hip/hip_runtime.h>
#include <hip/hip_bf16.h>

#define B_ 16
#define N_ 4096
#define S_ 1024
#define K_ 32
#define D_ 64
#define M_ (B_*S_*K_)            // 524288 rows
#define EPS_ 1e-5f

#define OUT_NRM  (B_*S_*3)       // 49152
#define OUT_FEAT (2*B_*S_*3)     // 98304
#define OUT_FPS  (OUT_FEAT + B_*S_*128)  // 2195456

// stats (float idx): S1=0 Q1=64 S2=128 Q2=192 S3=256(128) Q3=384(128)
//                    a1=512 s1=576 a2=640 s2=704 a3=768(128) s3=896(128)

typedef __attribute__((ext_vector_type(8))) short bf16x8;
typedef __attribute__((ext_vector_type(4))) float f32x4;

__device__ __forceinline__ unsigned short rnb(float x){
  return (unsigned short)((__float_as_uint(x) + 0x8000u) >> 16);
}
__device__ __forceinline__ void split1(float x, short& h, short& l){
  unsigned ux = __float_as_uint(x);
  unsigned uh = (ux + 0x8000u) & 0xFFFF0000u;
  h = (short)(uh >> 16);
  float lo = x - __uint_as_float(uh);
  l = (short)((__float_as_uint(lo) + 0x8000u) >> 16);
}

template<int V>
__device__ __forceinline__ void butterfly_sum(float* vals, int lr){
  int n = V;
  #pragma unroll
  for (int m = 8; m >= 1; m >>= 1){
    n >>= 1;
    bool hi = (lr & m) != 0;
    #pragma unroll
    for (int i = 0; i < n; i++){
      float send = hi ? vals[i] : vals[i+n];
      float recv = __shfl_xor(send, m);
      float keep = hi ? vals[i+n] : vals[i];
      vals[i] = keep + recv;
    }
  }
}
template<int V>
__device__ __forceinline__ void butterfly_max(float* vals, int lr){
  int n = V;
  #pragma unroll
  for (int m = 8; m >= 1; m >>= 1){
    n >>= 1;
    bool hi = (lr & m) != 0;
    #pragma unroll
    for (int i = 0; i < n; i++){
      float send = hi ? vals[i] : vals[i+n];
      float recv = __shfl_xor(send, m);
      float keep = hi ? vals[i+n] : vals[i];
      vals[i] = fmaxf(keep, recv);
    }
  }
}

__global__ void zero_stats_kernel(float* __restrict__ stats){
  int t = blockIdx.x*256 + threadIdx.x;
  if (t < 512) stats[t] = 0.f;
}

__global__ void meta_kernel(const float* __restrict__ xyz, const float* __restrict__ nrm,
                            const int* __restrict__ fps, float* __restrict__ out){
  int t = blockIdx.x*256 + threadIdx.x;
  if (t >= B_*S_) return;
  int b = t >> 10;
  int n = fps[t];
  const float* xp = xyz + ((size_t)b*N_ + n)*3;
  out[t*3+0] = xp[0]; out[t*3+1] = xp[1]; out[t*3+2] = xp[2];
  const float* pp = nrm + ((size_t)b*N_ + n)*3;
  out[OUT_NRM + t*3+0] = pp[0]; out[OUT_NRM + t*3+1] = pp[1]; out[OUT_NRM + t*3+2] = pp[2];
  out[OUT_FPS + t] = (float)n;
}

__global__ void prepack_kernel(const float* __restrict__ xyz, float4* __restrict__ packed){
  int t = blockIdx.x*256 + threadIdx.x;
  if (t >= B_*N_) return;
  float x = xyz[t*3+0], y = xyz[t*3+1], z = xyz[t*3+2];
  float pp = __fadd_rn(__fadd_rn(__fmul_rn(x,x), __fmul_rn(y,y)), __fmul_rn(z,z));
  packed[t] = make_float4(x, y, z, pp);
}

// pack W into per-lane MFMA A-fragments (bf16). elems: w0 [0,4096) w1 [4096,8192) w2 [8192,16384)
__global__ void packw_kernel(const float* __restrict__ w0, const float* __restrict__ w1,
                             const float* __restrict__ w2, unsigned short* __restrict__ dst){
  int e = blockIdx.x*256 + threadIdx.x;
  if (e >= 16384) return;
  const float* W; int base;
  if (e < 4096){ W = w0; base = 0; }
  else if (e < 8192){ W = w1; base = 4096; }
  else { W = w2; base = 8192; }
  int r = e - base;
  int frag = r >> 9;          // (cht*2 + ks)
  int lane = (r >> 3) & 63;
  int j = r & 7;
  int cht = frag >> 1, ks = frag & 1;
  int m = lane & 15, quad = lane >> 4;
  int ch = cht*16 + m, k = ks*32 + quad*8 + j;
  dst[e] = rnb(W[ch*64 + k]);
}

// ---------------- KNN (unchanged from R1) ----------------
__global__ __launch_bounds__(256, 3) void knn_kernel(const float4* __restrict__ packed,
                                                     const int* __restrict__ fps,
                                                     int* __restrict__ idxout){
  __shared__ unsigned skey[4][64];
  __shared__ int      sidx[4][64];
  const int w = threadIdx.x >> 6;
  const int l = threadIdx.x & 63;
  const int q = blockIdx.x*4 + w;
  const int b = q >> 10;
  const float4* pb = packed + (size_t)b*N_;
  const int nq = fps[q];
  const float4 qp = pb[nq];
  const float qx = qp.x, qy = qp.y, qz = qp.z, qq = qp.w;

  unsigned key[64];
  unsigned minkey = 0xFFFFFFFFu;
  #pragma unroll
  for (int i = 0; i < 64; i++){
    float4 p = pb[i*64 + l];
    float dt = __fadd_rn(__fadd_rn(__fmul_rn(qx,p.x), __fmul_rn(qy,p.y)), __fmul_rn(qz,p.z));
    float d  = __fsub_rn(__fadd_rn(qq,p.w), __fmul_rn(2.f,dt));
    unsigned u = __float_as_uint(d);
    u ^= (unsigned)(((int)u >> 31)) | 0x80000000u;
    key[i] = u;
    minkey = min(minkey, u);
  }
  {
    unsigned v = minkey;
    #pragma unroll
    for (int k = 2; k <= 64; k <<= 1){
      #pragma unroll
      for (int j = k >> 1; j > 0; j >>= 1){
        unsigned o = (unsigned)__shfl_xor((int)v, j);
        bool keepmin = (((l & k) == 0)) ^ ((l & j) != 0);
        unsigned mn = min(v, o), mx = max(v, o);
        v = keepmin ? mn : mx;
      }
    }
    minkey = v;
  }
  const unsigned T = (unsigned)__shfl((int)minkey, 31);

  int c = 0;
  #pragma unroll
  for (int i = 0; i < 64; i++) c += (key[i] <= T) ? 1 : 0;
  int inc = c;
  #pragma unroll
  for (int off = 1; off < 64; off <<= 1){
    int t2 = __shfl_up(inc, off);
    if (l >= off) inc += t2;
  }
  const int excl = inc - c;
  const int total = __shfl(inc, 63);

  const size_t obase = (size_t)q * K_;
  if (total <= 64){
    int off = excl;
    #pragma unroll
    for (int i = 0; i < 64; i++){
      if (key[i] <= T){
        skey[w][off] = key[i];
        sidx[w][off] = i*64 + l;
        off++;
      }
    }
    unsigned mykey = 0xFFFFFFFFu, myidx = 0xFFFFFFFFu;
    if (l < total){ mykey = skey[w][l]; myidx = (unsigned)sidx[w][l]; }
    unsigned long long sk = ((unsigned long long)mykey << 32) | (unsigned long long)myidx;
    #pragma unroll
    for (int k = 2; k <= 64; k <<= 1){
      #pragma unroll
      for (int j = k >> 1; j > 0; j >>= 1){
        unsigned long long o = __shfl_xor(sk, j);
        bool keepmin = (((l & k) == 0)) ^ ((l & j) != 0);
        unsigned long long mn = (sk < o) ? sk : o;
        unsigned long long mx = (sk < o) ? o : sk;
        sk = keepmin ? mn : mx;
      }
    }
    if (l < 32) idxout[obase + l] = (int)(unsigned)(sk & 0xFFFFFFFFull);
  } else {
    unsigned long long lo = 0, hi = (1ull << 44) - 1;
    for (int it = 0; it < 44; ++it){
      unsigned long long mid = (lo + hi) >> 1;
      unsigned midk = (unsigned)(mid >> 12);
      unsigned midi = (unsigned)(mid & 0xFFFull);
      int cc = 0;
      #pragma unroll
      for (int i = 0; i < 64; i++){
        unsigned n = (unsigned)(i*64 + l);
        cc += (key[i] < midk || (key[i] == midk && n <= midi)) ? 1 : 0;
      }
      #pragma unroll
      for (int o2 = 32; o2 > 0; o2 >>= 1) cc += __shfl_xor(cc, o2);
      if (cc >= 32) hi = mid; else lo = mid + 1;
    }
    const unsigned Ck = (unsigned)(lo >> 12);
    const unsigned Ci = (unsigned)(lo & 0xFFFull);
    int c2 = 0;
    #pragma unroll
    for (int i = 0; i < 64; i++){
      unsigned n = (unsigned)(i*64 + l);
      c2 += (key[i] < Ck || (key[i] == Ck && n <= Ci)) ? 1 : 0;
    }
    int inc2 = c2;
    #pragma unroll
    for (int off = 1; off < 64; off <<= 1){
      int t2 = __shfl_up(inc2, off);
      if (l >= off) inc2 += t2;
    }
    int off3 = inc2 - c2;
    #pragma unroll
    for (int i = 0; i < 64; i++){
      unsigned n = (unsigned)(i*64 + l);
      if (key[i] < Ck || (key[i] == Ck && n <= Ci)){
        sidx[w][off3] = i*64 + l;
        off3++;
      }
    }
    if (l < 32) idxout[obase + l] = sidx[w][l];
  }
}

// ---------------- conv1: gather(points) -> MFMA -> Y1 (tiled bf16) + stats ----------------
__global__ __launch_bounds__(256) void conv1_mfma(const float* __restrict__ pts,
    const int* __restrict__ idx, const unsigned short* __restrict__ wpk,
    const float* __restrict__ bias, unsigned short* __restrict__ Yo,
    float* __restrict__ stats){
  __shared__ float sred[4][128];
  const int t = threadIdx.x, w = t>>6, l = t&63, quad = l>>4, lr = l&15;
  const int m0 = blockIdx.x*128;
  const int Rw = m0 + w*32;
  const int b = m0 >> 15;
  bf16x8 wf[4][2];
  #pragma unroll
  for (int c = 0; c < 4; c++)
    #pragma unroll
    for (int s = 0; s < 2; s++)
      wf[c][s] = *(const bf16x8*)(wpk + (((c*2+s)<<6) + l)*8);
  f32x4 acc[4][2];
  #pragma unroll
  for (int c = 0; c < 4; c++){
    acc[c][0] = (f32x4){0.f,0.f,0.f,0.f};
    acc[c][1] = (f32x4){0.f,0.f,0.f,0.f};
  }
  #pragma unroll
  for (int rt = 0; rt < 2; rt++){
    int row = Rw + rt*16 + lr;
    int ri = idx[row];
    const float* pr = pts + ((size_t)(b*4096 + ri))*64;
    #pragma unroll
    for (int s = 0; s < 2; s++){
      float4 v0 = *(const float4*)(pr + s*32 + quad*8);
      float4 v1 = *(const float4*)(pr + s*32 + quad*8 + 4);
      float xs[8] = {v0.x,v0.y,v0.z,v0.w,v1.x,v1.y,v1.z,v1.w};
      bf16x8 xh, xl;
      #pragma unroll
      for (int j = 0; j < 8; j++){ short hh, ll; split1(xs[j], hh, ll); xh[j]=hh; xl[j]=ll; }
      #pragma unroll
      for (int c = 0; c < 4; c++){
        acc[c][rt] = __builtin_amdgcn_mfma_f32_16x16x32_bf16(wf[c][s], xh, acc[c][rt], 0,0,0);
        acc[c][rt] = __builtin_amdgcn_mfma_f32_16x16x32_bf16(wf[c][s], xl, acc[c][rt], 0,0,0);
      }
    }
  }
  float vals[32];
  const int rtg0 = Rw >> 4;
  #pragma unroll
  for (int c = 0; c < 4; c++){
    float4 bq = *(const float4*)(bias + c*16 + quad*4);
    float bqa[4] = {bq.x, bq.y, bq.z, bq.w};
    float y0[4], y1[4];
    #pragma unroll
    for (int r = 0; r < 4; r++){
      y0[r] = acc[c][0][r] + bqa[r];
      y1[r] = acc[c][1][r] + bqa[r];
      vals[c*4+r] = y0[r] + y1[r];
      vals[16+c*4+r] = y0[r]*y0[r] + y1[r]*y1[r];
    }
    uint2 p0, p1;
    p0.x = (unsigned)rnb(y0[0]) | ((unsigned)rnb(y0[1])<<16);
    p0.y = (unsigned)rnb(y0[2]) | ((unsigned)rnb(y0[3])<<16);
    p1.x = (unsigned)rnb(y1[0]) | ((unsigned)rnb(y1[1])<<16);
    p1.y = (unsigned)rnb(y1[2]) | ((unsigned)rnb(y1[3])<<16);
    int kb = c*2 + (quad>>1);
    int sub = (quad&1)*4;
    *(uint2*)(Yo + ((((rtg0+0)*8 + kb)*16 + lr)*8 + sub)) = p0;
    *(uint2*)(Yo + ((((rtg0+1)*8 + kb)*16 + lr)*8 + sub)) = p1;
  }
  butterfly_sum<32>(vals, lr);
  {
    bool isQ = (lr >= 8);
    int v2 = isQ ? 2*lr-16 : 2*lr;
    int sidx2 = (isQ?64:0) + (v2>>2)*16 + quad*4 + (v2&3);
    sred[w][sidx2] = vals[0]; sred[w][sidx2+1] = vals[1];
  }
  __syncthreads();
  if (t < 128){
    float tot = sred[0][t]+sred[1][t]+sred[2][t]+sred[3][t];
    unsafeAtomicAdd(&stats[t], tot);
  }
}

// ---------------- conv2: Y1 -> affine+relu -> MFMA -> Y2 + stats ----------------
__global__ __launch_bounds__(256) void conv2_mfma(const unsigned short* __restrict__ Yi,
    const unsigned short* __restrict__ wpk, const float* __restrict__ bias,
    const float* __restrict__ aff, unsigned short* __restrict__ Yo,
    float* __restrict__ stats){
  __shared__ float sred[4][128];
  const int t = threadIdx.x, w = t>>6, l = t&63, quad = l>>4, lr = l&15;
  const int m0 = blockIdx.x*128;
  const int Rw = m0 + w*32;
  bf16x8 wf[4][2];
  #pragma unroll
  for (int c = 0; c < 4; c++)
    #pragma unroll
    for (int s = 0; s < 2; s++)
      wf[c][s] = *(const bf16x8*)(wpk + (((c*2+s)<<6) + l)*8);
  f32x4 acc[4][2];
  #pragma unroll
  for (int c = 0; c < 4; c++){
    acc[c][0] = (f32x4){0.f,0.f,0.f,0.f};
    acc[c][1] = (f32x4){0.f,0.f,0.f,0.f};
  }
  const float* affA = aff;
  const float* affB = aff + 64;
  const int rtg0 = Rw >> 4;
  #pragma unroll
  for (int rt = 0; rt < 2; rt++){
    #pragma unroll
    for (int s = 0; s < 2; s++){
      uint4 u = *(const uint4*)(Yi + (((rtg0+rt)*8 + s*4 + quad)*16 + lr)*8);
      unsigned ua[4] = {u.x,u.y,u.z,u.w};
      float4 A0 = *(const float4*)(affA + s*32 + quad*8);
      float4 A1 = *(const float4*)(affA + s*32 + quad*8 + 4);
      float4 B0 = *(const float4*)(affB + s*32 + quad*8);
      float4 B1 = *(const float4*)(affB + s*32 + quad*8 + 4);
      float aA[8] = {A0.x,A0.y,A0.z,A0.w,A1.x,A1.y,A1.z,A1.w};
      float aB[8] = {B0.x,B0.y,B0.z,B0.w,B1.x,B1.y,B1.z,B1.w};
      bf16x8 xh, xl;
      #pragma unroll
      for (int j = 0; j < 8; j++){
        unsigned wd = ua[j>>1];
        float yf = __uint_as_float((j&1) ? (wd & 0xFFFF0000u) : (wd << 16));
        float x = fmaxf(0.f, fmaf(yf, aA[j], aB[j]));
        short hh, ll; split1(x, hh, ll); xh[j]=hh; xl[j]=ll;
      }
      #pragma unroll
      for (int c = 0; c < 4; c++){
        acc[c][rt] = __builtin_amdgcn_mfma_f32_16x16x32_bf16(wf[c][s], xh, acc[c][rt], 0,0,0);
        acc[c][rt] = __builtin_amdgcn_mfma_f32_16x16x32_bf16(wf[c][s], xl, acc[c][rt], 0,0,0);
      }
    }
  }
  float vals[32];
  #pragma unroll
  for (int c = 0; c < 4; c++){
    float4 bq = *(const float4*)(bias + c*16 + quad*4);
    float bqa[4] = {bq.x, bq.y, bq.z, bq.w};
    float y0[4], y1[4];
    #pragma unroll
    for (int r = 0; r < 4; r++){
      y0[r] = acc[c][0][r] + bqa[r];
      y1[r] = acc[c][1][r] + bqa[r];
      vals[c*4+r] = y0[r] + y1[r];
      vals[16+c*4+r] = y0[r]*y0[r] + y1[r]*y1[r];
    }
    uint2 p0, p1;
    p0.x = (unsigned)rnb(y0[0]) | ((unsigned)rnb(y0[1])<<16);
    p0.y = (unsigned)rnb(y0[2]) | ((unsigned)rnb(y0[3])<<16);
    p1.x = (unsigned)rnb(y1[0]) | ((unsigned)rnb(y1[1])<<16);
    p1.y = (unsigned)rnb(y1[2]) | ((unsigned)rnb(y1[3])<<16);
    int kb = c*2 + (quad>>1);
    int sub = (quad&1)*4;
    *(uint2*)(Yo + ((((rtg0+0)*8 + kb)*16 + lr)*8 + sub)) = p0;
    *(uint2*)(Yo + ((((rtg0+1)*8 + kb)*16 + lr)*8 + sub)) = p1;
  }
  butterfly_sum<32>(vals, lr);
  {
    bool isQ = (lr >= 8);
    int v2 = isQ ? 2*lr-16 : 2*lr;
    int sidx2 = (isQ?64:0) + (v2>>2)*16 + quad*4 + (v2&3);
    sred[w][sidx2] = vals[0]; sred[w][sidx2+1] = vals[1];
  }
  __syncthreads();
  if (t < 128){
    float tot = sred[0][t]+sred[1][t]+sred[2][t]+sred[3][t];
    unsafeAtomicAdd(&stats[128 + t], tot);
  }
}

// ---------------- conv3: Y2 -> affine+relu -> MFMA -> K-maxpool + stats ----------------
__global__ __launch_bounds__(256) void conv3_mfma(const unsigned short* __restrict__ Yi,
    const unsigned short* __restrict__ wpk, const float* __restrict__ bias,
    const float* __restrict__ aff, float* __restrict__ ymax,
    float* __restrict__ stats){
  __shared__ float sred[4][256];
  const int t = threadIdx.x, w = t>>6, l = t&63, quad = l>>4, lr = l&15;
  const int m0 = blockIdx.x*128;
  const int Rw = m0 + w*32;
  bf16x8 wf[8][2];
  #pragma unroll
  for (int c = 0; c < 8; c++)
    #pragma unroll
    for (int s = 0; s < 2; s++)
      wf[c][s] = *(const bf16x8*)(wpk + (((c*2+s)<<6) + l)*8);
  f32x4 acc[8][2];
  #pragma unroll
  for (int c = 0; c < 8; c++){
    acc[c][0] = (f32x4){0.f,0.f,0.f,0.f};
    acc[c][1] = (f32x4){0.f,0.f,0.f,0.f};
  }
  const float* affA = aff;
  const float* affB = aff + 64;
  const int rtg0 = Rw >> 4;
  #pragma unroll
  for (int rt = 0; rt < 2; rt++){
    #pragma unroll
    for (int s = 0; s < 2; s++){
      uint4 u = *(const uint4*)(Yi + (((rtg0+rt)*8 + s*4 + quad)*16 + lr)*8);
      unsigned ua[4] = {u.x,u.y,u.z,u.w};
      float4 A0 = *(const float4*)(affA + s*32 + quad*8);
      float4 A1 = *(const float4*)(affA + s*32 + quad*8 + 4);
      float4 B0 = *(const float4*)(affB + s*32 + quad*8);
      float4 B1 = *(const float4*)(affB + s*32 + quad*8 + 4);
      float aA[8] = {A0.x,A0.y,A0.z,A0.w,A1.x,A1.y,A1.z,A1.w};
      float aB[8] = {B0.x,B0.y,B0.z,B0.w,B1.x,B1.y,B1.z,B1.w};
      bf16x8 xh, xl;
      #pragma unroll
      for (int j = 0; j < 8; j++){
        unsigned wd = ua[j>>1];
        float yf = __uint_as_float((j&1) ? (wd & 0xFFFF0000u) : (wd << 16));
        float x = fmaxf(0.f, fmaf(yf, aA[j], aB[j]));
        short hh, ll; split1(x, hh, ll); xh[j]=hh; xl[j]=ll;
      }
      #pragma unroll
      for (int c = 0; c < 8; c++){
        acc[c][rt] = __builtin_amdgcn_mfma_f32_16x16x32_bf16(wf[c][s], xh, acc[c][rt], 0,0,0);
        acc[c][rt] = __builtin_amdgcn_mfma_f32_16x16x32_bf16(wf[c][s], xl, acc[c][rt], 0,0,0);
      }
    }
  }
  float vals[64];
  float mvals[32];
  #pragma unroll
  for (int c = 0; c < 8; c++){
    float4 bq = *(const float4*)(bias + c*16 + quad*4);
    float bqa[4] = {bq.x, bq.y, bq.z, bq.w};
    #pragma unroll
    for (int r = 0; r < 4; r++){
      float y0 = acc[c][0][r] + bqa[r];
      float y1 = acc[c][1][r] + bqa[r];
      vals[c*4+r] = y0 + y1;
      vals[32+c*4+r] = y0*y0 + y1*y1;
      mvals[c*4+r] = fmaxf(y0, y1);
    }
  }
  butterfly_max<32>(mvals, lr);
  {
    const int g = Rw >> 5;     // group = b*S + s
    int v2 = 2*lr;
    int ch0 = (v2>>2)*16 + quad*4 + (v2&3);
    float2 mv = make_float2(mvals[0], mvals[1]);
    *(float2*)(ymax + (size_t)g*128 + ch0) = mv;
  }
  butterfly_sum<64>(vals, lr);
  {
    bool isQ = (lr >= 8);
    int c = isQ ? (lr-8) : lr;
    int sidx2 = (isQ?128:0) + c*16 + quad*4;
    sred[w][sidx2+0] = vals[0]; sred[w][sidx2+1] = vals[1];
    sred[w][sidx2+2] = vals[2]; sred[w][sidx2+3] = vals[3];
  }
  __syncthreads();
  {
    float tot = sred[0][t]+sred[1][t]+sred[2][t]+sred[3][t];
    unsafeAtomicAdd(&stats[256 + t], tot);
  }
}

__global__ void bnparam_kernel(const float* __restrict__ stats, const float* __restrict__ g,
                               const float* __restrict__ bt, float* __restrict__ outAS,
                               int sOff, int qOff, int C){
  int c = threadIdx.x;
  if (c >= C) return;
  const float inv = 1.f/(float)M_;
  float mean = stats[sOff + c] * inv;
  float var  = stats[qOff + c] * inv - mean*mean;
  float a = g[c] * rsqrtf(var + EPS_);
  outAS[c] = a;
  outAS[C + c] = bt[c] - mean*a;
}

__global__ void final_kernel(const float* __restrict__ ymax,
                             const float* __restrict__ stats, float* __restrict__ out){
  int t = blockIdx.x*256 + threadIdx.x;     // (b*S+s)*128 + o
  int o = t & 127;
  float a = stats[768 + o], s = stats[896 + o];
  // g=ones => a = rsqrt(var+eps) > 0, so max commutes with the affine+relu
  out[OUT_FEAT + t] = fmaxf(0.f, a*ymax[t] + s);
}

extern "C" void kernel_launch(void* const* d_in, const int* in_sizes, int n_in,
                              void* d_out, int out_size, void* d_ws, size_t ws_size,
                              hipStream_t stream) {
  const float* xyz = (const float*)d_in[0];
  const float* nrm = (const float*)d_in[1];
  const float* pts = (const float*)d_in[2];
  const int*   fps = (const int*)d_in[3];
  const float* w0  = (const float*)d_in[4];
  const float* b0  = (const float*)d_in[5];
  const float* g0  = (const float*)d_in[6];
  const float* bt0 = (const float*)d_in[7];
  const float* w1  = (const float*)d_in[8];
  const float* b1  = (const float*)d_in[9];
  const float* g1  = (const float*)d_in[10];
  const float* bt1 = (const float*)d_in[11];
  const float* w2  = (const float*)d_in[12];
  const float* b2  = (const float*)d_in[13];
  const float* g2  = (const float*)d_in[14];
  const float* bt2 = (const float*)d_in[15];
  float* out = (float*)d_out;

  char* ws = (char*)d_ws;
  float* stats = (float*)ws;                                  // 4 KB (same as R1)
  int*   idxb  = (int*)(ws + 4096);                           // 2 MB
  float* ymax  = (float*)(ws + 2101248);                      // 8 MB
  float4* packed = (float4*)(ws + 10489856);                  // 1 MB (old ymin slot)
  unsigned short* wpack = (unsigned short*)(ws + 11538432);   // 32 KB (old ymin slot)
  unsigned short* Y1 = (unsigned short*)(ws + 18878464);      // 64 MB
  unsigned short* Y2 = (unsigned short*)(ws + 85987328);      // 64 MB (ends 153096192)

  zero_stats_kernel<<<2, 256, 0, stream>>>(stats);
  meta_kernel<<<64, 256, 0, stream>>>(xyz, nrm, fps, out);
  prepack_kernel<<<256, 256, 0, stream>>>(xyz, packed);
  packw_kernel<<<64, 256, 0, stream>>>(w0, w1, w2, wpack);
  knn_kernel<<<4096, 256, 0, stream>>>(packed, fps, idxb);
  conv1_mfma<<<4096, 256, 0, stream>>>(pts, idxb, wpack, b0, Y1, stats);
  bnparam_kernel<<<1, 64, 0, stream>>>(stats, g0, bt0, stats + 512, 0, 64, 64);
  conv2_mfma<<<4096, 256, 0, stream>>>(Y1, wpack + 4096, b1, stats + 512, Y2, stats);
  bnparam_kernel<<<1, 64, 0, stream>>>(stats, g1, bt1, stats + 640, 128, 192, 64);
  conv3_mfma<<<4096, 256, 0, stream>>>(Y2, wpack + 8192, b2, stats + 640, ymax, stats);
  bnparam_kernel<<<1, 128, 0, stream>>>(stats, g2, bt2, stats + 768, 256, 384, 128);
  final_kernel<<<8192, 256, 0, stream>>>(ymax, stats, out);
}

// Round 4
// 526.725 us; speedup vs baseline: 2.0145x; 1.2629x over previous
//
#include <hip/hip_runtime.h>
#include <hip/hip_bf16.h>

#define B_ 16
#define N_ 4096
#define S_ 1024
#define K_ 32
#define D_ 64
#define M_ (B_*S_*K_)            // 524288 rows
#define EPS_ 1e-5f

#define OUT_NRM  (B_*S_*3)       // 49152
#define OUT_FEAT (2*B_*S_*3)     // 98304
#define OUT_FPS  (OUT_FEAT + B_*S_*128)  // 2195456

// stats (float idx): S1=0 Q1=64 S2=128 Q2=192 S3=256(128) Q3=384(128)
//                    a1=512 s1=576 a2=640 s2=704 a3=768(128) s3=896(128)

typedef __attribute__((ext_vector_type(8))) short bf16x8;
typedef __attribute__((ext_vector_type(4))) float f32x4;

__device__ __forceinline__ unsigned short rnb(float x){
  return (unsigned short)((__float_as_uint(x) + 0x8000u) >> 16);
}
__device__ __forceinline__ void split1(float x, short& h, short& l){
  unsigned ux = __float_as_uint(x);
  unsigned uh = (ux + 0x8000u) & 0xFFFF0000u;
  h = (short)(uh >> 16);
  float lo = x - __uint_as_float(uh);
  l = (short)((__float_as_uint(lo) + 0x8000u) >> 16);
}

// reduce 4 values across the 16 lr-lanes; result: lane with bits(3,2)=(b3,b2)
// holds total of v[2*b3+b2]; duplicated across bits(1,0).
__device__ __forceinline__ float hred4_sum(const float v[4], int l){
  bool hi8 = (l & 8) != 0;
  float send0 = hi8 ? v[0] : v[2];
  float send1 = hi8 ? v[1] : v[3];
  float r0 = __shfl_xor(send0, 8);
  float r1 = __shfl_xor(send1, 8);
  float a0 = (hi8 ? v[2] : v[0]) + r0;
  float a1 = (hi8 ? v[3] : v[1]) + r1;
  bool hi4 = (l & 4) != 0;
  float send = hi4 ? a0 : a1;
  float r = __shfl_xor(send, 4);
  float a = (hi4 ? a1 : a0) + r;
  a += __shfl_xor(a, 2);
  a += __shfl_xor(a, 1);
  return a;
}
__device__ __forceinline__ float hred4_max(const float v[4], int l){
  bool hi8 = (l & 8) != 0;
  float send0 = hi8 ? v[0] : v[2];
  float send1 = hi8 ? v[1] : v[3];
  float r0 = __shfl_xor(send0, 8);
  float r1 = __shfl_xor(send1, 8);
  float a0 = fmaxf(hi8 ? v[2] : v[0], r0);
  float a1 = fmaxf(hi8 ? v[3] : v[1], r1);
  bool hi4 = (l & 4) != 0;
  float send = hi4 ? a0 : a1;
  float r = __shfl_xor(send, 4);
  float a = fmaxf(hi4 ? a1 : a0, r);
  a = fmaxf(a, __shfl_xor(a, 2));
  a = fmaxf(a, __shfl_xor(a, 1));
  return a;
}

__global__ void zero_stats_kernel(float* __restrict__ stats){
  int t = blockIdx.x*256 + threadIdx.x;
  if (t < 512) stats[t] = 0.f;
}

__global__ void meta_kernel(const float* __restrict__ xyz, const float* __restrict__ nrm,
                            const int* __restrict__ fps, float* __restrict__ out){
  int t = blockIdx.x*256 + threadIdx.x;
  if (t >= B_*S_) return;
  int b = t >> 10;
  int n = fps[t];
  const float* xp = xyz + ((size_t)b*N_ + n)*3;
  out[t*3+0] = xp[0]; out[t*3+1] = xp[1]; out[t*3+2] = xp[2];
  const float* pp = nrm + ((size_t)b*N_ + n)*3;
  out[OUT_NRM + t*3+0] = pp[0]; out[OUT_NRM + t*3+1] = pp[1]; out[OUT_NRM + t*3+2] = pp[2];
  out[OUT_FPS + t] = (float)n;
}

__global__ void prepack_kernel(const float* __restrict__ xyz, float4* __restrict__ packed){
  int t = blockIdx.x*256 + threadIdx.x;
  if (t >= B_*N_) return;
  float x = xyz[t*3+0], y = xyz[t*3+1], z = xyz[t*3+2];
  float pp = __fadd_rn(__fadd_rn(__fmul_rn(x,x), __fmul_rn(y,y)), __fmul_rn(z,z));
  packed[t] = make_float4(x, y, z, pp);
}

// pack W into per-lane MFMA A-fragments (bf16). elems: w0 [0,4096) w1 [4096,8192) w2 [8192,16384)
__global__ void packw_kernel(const float* __restrict__ w0, const float* __restrict__ w1,
                             const float* __restrict__ w2, unsigned short* __restrict__ dst){
  int e = blockIdx.x*256 + threadIdx.x;
  if (e >= 16384) return;
  const float* W; int base;
  if (e < 4096){ W = w0; base = 0; }
  else if (e < 8192){ W = w1; base = 4096; }
  else { W = w2; base = 8192; }
  int r = e - base;
  int frag = r >> 9;          // (cht*2 + ks)
  int lane = (r >> 3) & 63;
  int j = r & 7;
  int cht = frag >> 1, ks = frag & 1;
  int m = lane & 15, quad = lane >> 4;
  int ch = cht*16 + m, k = ks*32 + quad*8 + j;
  dst[e] = rnb(W[ch*64 + k]);
}

// ---------------- KNN (unchanged) ----------------
__global__ __launch_bounds__(256, 3) void knn_kernel(const float4* __restrict__ packed,
                                                     const int* __restrict__ fps,
                                                     int* __restrict__ idxout){
  __shared__ unsigned skey[4][64];
  __shared__ int      sidx[4][64];
  const int w = threadIdx.x >> 6;
  const int l = threadIdx.x & 63;
  const int q = blockIdx.x*4 + w;
  const int b = q >> 10;
  const float4* pb = packed + (size_t)b*N_;
  const int nq = fps[q];
  const float4 qp = pb[nq];
  const float qx = qp.x, qy = qp.y, qz = qp.z, qq = qp.w;

  unsigned key[64];
  unsigned minkey = 0xFFFFFFFFu;
  #pragma unroll
  for (int i = 0; i < 64; i++){
    float4 p = pb[i*64 + l];
    float dt = __fadd_rn(__fadd_rn(__fmul_rn(qx,p.x), __fmul_rn(qy,p.y)), __fmul_rn(qz,p.z));
    float d  = __fsub_rn(__fadd_rn(qq,p.w), __fmul_rn(2.f,dt));
    unsigned u = __float_as_uint(d);
    u ^= (unsigned)(((int)u >> 31)) | 0x80000000u;
    key[i] = u;
    minkey = min(minkey, u);
  }
  {
    unsigned v = minkey;
    #pragma unroll
    for (int k = 2; k <= 64; k <<= 1){
      #pragma unroll
      for (int j = k >> 1; j > 0; j >>= 1){
        unsigned o = (unsigned)__shfl_xor((int)v, j);
        bool keepmin = (((l & k) == 0)) ^ ((l & j) != 0);
        unsigned mn = min(v, o), mx = max(v, o);
        v = keepmin ? mn : mx;
      }
    }
    minkey = v;
  }
  const unsigned T = (unsigned)__shfl((int)minkey, 31);

  int c = 0;
  #pragma unroll
  for (int i = 0; i < 64; i++) c += (key[i] <= T) ? 1 : 0;
  int inc = c;
  #pragma unroll
  for (int off = 1; off < 64; off <<= 1){
    int t2 = __shfl_up(inc, off);
    if (l >= off) inc += t2;
  }
  const int excl = inc - c;
  const int total = __shfl(inc, 63);

  const size_t obase = (size_t)q * K_;
  if (total <= 64){
    int off = excl;
    #pragma unroll
    for (int i = 0; i < 64; i++){
      if (key[i] <= T){
        skey[w][off] = key[i];
        sidx[w][off] = i*64 + l;
        off++;
      }
    }
    unsigned mykey = 0xFFFFFFFFu, myidx = 0xFFFFFFFFu;
    if (l < total){ mykey = skey[w][l]; myidx = (unsigned)sidx[w][l]; }
    unsigned long long sk = ((unsigned long long)mykey << 32) | (unsigned long long)myidx;
    #pragma unroll
    for (int k = 2; k <= 64; k <<= 1){
      #pragma unroll
      for (int j = k >> 1; j > 0; j >>= 1){
        unsigned long long o = __shfl_xor(sk, j);
        bool keepmin = (((l & k) == 0)) ^ ((l & j) != 0);
        unsigned long long mn = (sk < o) ? sk : o;
        unsigned long long mx = (sk < o) ? o : sk;
        sk = keepmin ? mn : mx;
      }
    }
    if (l < 32) idxout[obase + l] = (int)(unsigned)(sk & 0xFFFFFFFFull);
  } else {
    unsigned long long lo = 0, hi = (1ull << 44) - 1;
    for (int it = 0; it < 44; ++it){
      unsigned long long mid = (lo + hi) >> 1;
      unsigned midk = (unsigned)(mid >> 12);
      unsigned midi = (unsigned)(mid & 0xFFFull);
      int cc = 0;
      #pragma unroll
      for (int i = 0; i < 64; i++){
        unsigned n = (unsigned)(i*64 + l);
        cc += (key[i] < midk || (key[i] == midk && n <= midi)) ? 1 : 0;
      }
      #pragma unroll
      for (int o2 = 32; o2 > 0; o2 >>= 1) cc += __shfl_xor(cc, o2);
      if (cc >= 32) hi = mid; else lo = mid + 1;
    }
    const unsigned Ck = (unsigned)(lo >> 12);
    const unsigned Ci = (unsigned)(lo & 0xFFFull);
    int c2 = 0;
    #pragma unroll
    for (int i = 0; i < 64; i++){
      unsigned n = (unsigned)(i*64 + l);
      c2 += (key[i] < Ck || (key[i] == Ck && n <= Ci)) ? 1 : 0;
    }
    int inc2 = c2;
    #pragma unroll
    for (int off = 1; off < 64; off <<= 1){
      int t2 = __shfl_up(inc2, off);
      if (l >= off) inc2 += t2;
    }
    int off3 = inc2 - c2;
    #pragma unroll
    for (int i = 0; i < 64; i++){
      unsigned n = (unsigned)(i*64 + l);
      if (key[i] < Ck || (key[i] == Ck && n <= Ci)){
        sidx[w][off3] = i*64 + l;
        off3++;
      }
    }
    if (l < 32) idxout[obase + l] = sidx[w][l];
  }
}

// ---------------- conv1: gather(points) -> MFMA -> Y1 (tiled bf16) + stats ----------------
__global__ __launch_bounds__(256, 2) void conv1_mfma(const float* __restrict__ pts,
    const int* __restrict__ idx, const unsigned short* __restrict__ wpk,
    const float* __restrict__ bias, unsigned short* __restrict__ Yo,
    float* __restrict__ stats){
  __shared__ float sred[4][128];
  const int t = threadIdx.x, w = t>>6, l = t&63, quad = l>>4, lr = l&15;
  const int m0 = blockIdx.x*128;
  const int Rw = m0 + w*32;
  const int b = m0 >> 15;
  bf16x8 wf[4][2];
  #pragma unroll
  for (int c = 0; c < 4; c++)
    #pragma unroll
    for (int s = 0; s < 2; s++)
      wf[c][s] = *(const bf16x8*)(wpk + (((c*2+s)<<6) + l)*8);
  f32x4 acc[4][2];
  #pragma unroll
  for (int c = 0; c < 4; c++){
    acc[c][0] = (f32x4){0.f,0.f,0.f,0.f};
    acc[c][1] = (f32x4){0.f,0.f,0.f,0.f};
  }
  #pragma unroll
  for (int rt = 0; rt < 2; rt++){
    int row = Rw + rt*16 + lr;
    int ri = idx[row];
    const float* pr = pts + ((size_t)(b*4096 + ri))*64;
    #pragma unroll
    for (int s = 0; s < 2; s++){
      float4 v0 = *(const float4*)(pr + s*32 + quad*8);
      float4 v1 = *(const float4*)(pr + s*32 + quad*8 + 4);
      float xs[8] = {v0.x,v0.y,v0.z,v0.w,v1.x,v1.y,v1.z,v1.w};
      bf16x8 xh, xl;
      #pragma unroll
      for (int j = 0; j < 8; j++){ short hh, ll; split1(xs[j], hh, ll); xh[j]=hh; xl[j]=ll; }
      #pragma unroll
      for (int c = 0; c < 4; c++){
        acc[c][rt] = __builtin_amdgcn_mfma_f32_16x16x32_bf16(wf[c][s], xh, acc[c][rt], 0,0,0);
        acc[c][rt] = __builtin_amdgcn_mfma_f32_16x16x32_bf16(wf[c][s], xl, acc[c][rt], 0,0,0);
      }
    }
  }
  const int rtg0 = Rw >> 4;
  #pragma unroll
  for (int c = 0; c < 4; c++){
    float4 bq = *(const float4*)(bias + c*16 + quad*4);
    float bqa[4] = {bq.x, bq.y, bq.z, bq.w};
    float y0[4], y1[4], sv[4], qv[4];
    #pragma unroll
    for (int r = 0; r < 4; r++){
      y0[r] = acc[c][0][r] + bqa[r];
      y1[r] = acc[c][1][r] + bqa[r];
      sv[r] = y0[r] + y1[r];
      qv[r] = y0[r]*y0[r] + y1[r]*y1[r];
    }
    uint2 p0, p1;
    p0.x = (unsigned)rnb(y0[0]) | ((unsigned)rnb(y0[1])<<16);
    p0.y = (unsigned)rnb(y0[2]) | ((unsigned)rnb(y0[3])<<16);
    p1.x = (unsigned)rnb(y1[0]) | ((unsigned)rnb(y1[1])<<16);
    p1.y = (unsigned)rnb(y1[2]) | ((unsigned)rnb(y1[3])<<16);
    int kb = c*2 + (quad>>1);
    int sub = (quad&1)*4;
    *(uint2*)(Yo + ((((rtg0+0)*8 + kb)*16 + lr)*8 + sub)) = p0;
    *(uint2*)(Yo + ((((rtg0+1)*8 + kb)*16 + lr)*8 + sub)) = p1;
    float S = hred4_sum(sv, l);
    float Q = hred4_sum(qv, l);
    if ((l & 3) == 0){
      int ch = c*16 + quad*4 + ((l>>3)&1)*2 + ((l>>2)&1);
      sred[w][ch] = S;
      sred[w][64 + ch] = Q;
    }
  }
  __syncthreads();
  if (t < 128){
    float tot = sred[0][t]+sred[1][t]+sred[2][t]+sred[3][t];
    unsafeAtomicAdd(&stats[t], tot);
  }
}

// ---------------- conv2: Y1 -> affine+relu -> MFMA -> Y2 + stats ----------------
__global__ __launch_bounds__(256, 2) void conv2_mfma(const unsigned short* __restrict__ Yi,
    const unsigned short* __restrict__ wpk, const float* __restrict__ bias,
    const float* __restrict__ aff, unsigned short* __restrict__ Yo,
    float* __restrict__ stats){
  __shared__ float sred[4][128];
  const int t = threadIdx.x, w = t>>6, l = t&63, quad = l>>4, lr = l&15;
  const int m0 = blockIdx.x*128;
  const int Rw = m0 + w*32;
  bf16x8 wf[4][2];
  #pragma unroll
  for (int c = 0; c < 4; c++)
    #pragma unroll
    for (int s = 0; s < 2; s++)
      wf[c][s] = *(const bf16x8*)(wpk + (((c*2+s)<<6) + l)*8);
  f32x4 acc[4][2];
  #pragma unroll
  for (int c = 0; c < 4; c++){
    acc[c][0] = (f32x4){0.f,0.f,0.f,0.f};
    acc[c][1] = (f32x4){0.f,0.f,0.f,0.f};
  }
  const float* affA = aff;
  const float* affB = aff + 64;
  const int rtg0 = Rw >> 4;
  #pragma unroll
  for (int rt = 0; rt < 2; rt++){
    #pragma unroll
    for (int s = 0; s < 2; s++){
      uint4 u = *(const uint4*)(Yi + (((rtg0+rt)*8 + s*4 + quad)*16 + lr)*8);
      unsigned ua[4] = {u.x,u.y,u.z,u.w};
      float4 A0 = *(const float4*)(affA + s*32 + quad*8);
      float4 A1 = *(const float4*)(affA + s*32 + quad*8 + 4);
      float4 B0 = *(const float4*)(affB + s*32 + quad*8);
      float4 B1 = *(const float4*)(affB + s*32 + quad*8 + 4);
      float aA[8] = {A0.x,A0.y,A0.z,A0.w,A1.x,A1.y,A1.z,A1.w};
      float aB[8] = {B0.x,B0.y,B0.z,B0.w,B1.x,B1.y,B1.z,B1.w};
      bf16x8 xh, xl;
      #pragma unroll
      for (int j = 0; j < 8; j++){
        unsigned wd = ua[j>>1];
        float yf = __uint_as_float((j&1) ? (wd & 0xFFFF0000u) : (wd << 16));
        float x = fmaxf(0.f, fmaf(yf, aA[j], aB[j]));
        short hh, ll; split1(x, hh, ll); xh[j]=hh; xl[j]=ll;
      }
      #pragma unroll
      for (int c = 0; c < 4; c++){
        acc[c][rt] = __builtin_amdgcn_mfma_f32_16x16x32_bf16(wf[c][s], xh, acc[c][rt], 0,0,0);
        acc[c][rt] = __builtin_amdgcn_mfma_f32_16x16x32_bf16(wf[c][s], xl, acc[c][rt], 0,0,0);
      }
    }
  }
  #pragma unroll
  for (int c = 0; c < 4; c++){
    float4 bq = *(const float4*)(bias + c*16 + quad*4);
    float bqa[4] = {bq.x, bq.y, bq.z, bq.w};
    float y0[4], y1[4], sv[4], qv[4];
    #pragma unroll
    for (int r = 0; r < 4; r++){
      y0[r] = acc[c][0][r] + bqa[r];
      y1[r] = acc[c][1][r] + bqa[r];
      sv[r] = y0[r] + y1[r];
      qv[r] = y0[r]*y0[r] + y1[r]*y1[r];
    }
    uint2 p0, p1;
    p0.x = (unsigned)rnb(y0[0]) | ((unsigned)rnb(y0[1])<<16);
    p0.y = (unsigned)rnb(y0[2]) | ((unsigned)rnb(y0[3])<<16);
    p1.x = (unsigned)rnb(y1[0]) | ((unsigned)rnb(y1[1])<<16);
    p1.y = (unsigned)rnb(y1[2]) | ((unsigned)rnb(y1[3])<<16);
    int kb = c*2 + (quad>>1);
    int sub = (quad&1)*4;
    *(uint2*)(Yo + ((((rtg0+0)*8 + kb)*16 + lr)*8 + sub)) = p0;
    *(uint2*)(Yo + ((((rtg0+1)*8 + kb)*16 + lr)*8 + sub)) = p1;
    float S = hred4_sum(sv, l);
    float Q = hred4_sum(qv, l);
    if ((l & 3) == 0){
      int ch = c*16 + quad*4 + ((l>>3)&1)*2 + ((l>>2)&1);
      sred[w][ch] = S;
      sred[w][64 + ch] = Q;
    }
  }
  __syncthreads();
  if (t < 128){
    float tot = sred[0][t]+sred[1][t]+sred[2][t]+sred[3][t];
    unsafeAtomicAdd(&stats[128 + t], tot);
  }
}

// ---------------- conv3: Y2 -> affine+relu -> MFMA -> K-maxpool + stats ----------------
__global__ __launch_bounds__(256, 2) void conv3_mfma(const unsigned short* __restrict__ Yi,
    const unsigned short* __restrict__ wpk, const float* __restrict__ bias,
    const float* __restrict__ aff, float* __restrict__ ymax,
    float* __restrict__ stats){
  __shared__ float sred[4][256];
  const int t = threadIdx.x, w = t>>6, l = t&63, quad = l>>4, lr = l&15;
  const int m0 = blockIdx.x*128;
  const int Rw = m0 + w*32;
  bf16x8 wf[8][2];
  #pragma unroll
  for (int c = 0; c < 8; c++)
    #pragma unroll
    for (int s = 0; s < 2; s++)
      wf[c][s] = *(const bf16x8*)(wpk + (((c*2+s)<<6) + l)*8);
  f32x4 acc[8][2];
  #pragma unroll
  for (int c = 0; c < 8; c++){
    acc[c][0] = (f32x4){0.f,0.f,0.f,0.f};
    acc[c][1] = (f32x4){0.f,0.f,0.f,0.f};
  }
  const float* affA = aff;
  const float* affB = aff + 64;
  const int rtg0 = Rw >> 4;
  #pragma unroll
  for (int rt = 0; rt < 2; rt++){
    #pragma unroll
    for (int s = 0; s < 2; s++){
      uint4 u = *(const uint4*)(Yi + (((rtg0+rt)*8 + s*4 + quad)*16 + lr)*8);
      unsigned ua[4] = {u.x,u.y,u.z,u.w};
      float4 A0 = *(const float4*)(affA + s*32 + quad*8);
      float4 A1 = *(const float4*)(affA + s*32 + quad*8 + 4);
      float4 B0 = *(const float4*)(affB + s*32 + quad*8);
      float4 B1 = *(const float4*)(affB + s*32 + quad*8 + 4);
      float aA[8] = {A0.x,A0.y,A0.z,A0.w,A1.x,A1.y,A1.z,A1.w};
      float aB[8] = {B0.x,B0.y,B0.z,B0.w,B1.x,B1.y,B1.z,B1.w};
      bf16x8 xh, xl;
      #pragma unroll
      for (int j = 0; j < 8; j++){
        unsigned wd = ua[j>>1];
        float yf = __uint_as_float((j&1) ? (wd & 0xFFFF0000u) : (wd << 16));
        float x = fmaxf(0.f, fmaf(yf, aA[j], aB[j]));
        short hh, ll; split1(x, hh, ll); xh[j]=hh; xl[j]=ll;
      }
      #pragma unroll
      for (int c = 0; c < 8; c++){
        acc[c][rt] = __builtin_amdgcn_mfma_f32_16x16x32_bf16(wf[c][s], xh, acc[c][rt], 0,0,0);
        acc[c][rt] = __builtin_amdgcn_mfma_f32_16x16x32_bf16(wf[c][s], xl, acc[c][rt], 0,0,0);
      }
    }
  }
  const int g = Rw >> 5;       // group = b*S + s (wave = exactly one K=32 group)
  #pragma unroll
  for (int c = 0; c < 8; c++){
    float4 bq = *(const float4*)(bias + c*16 + quad*4);
    float bqa[4] = {bq.x, bq.y, bq.z, bq.w};
    float sv[4], qv[4], mv[4];
    #pragma unroll
    for (int r = 0; r < 4; r++){
      float y0 = acc[c][0][r] + bqa[r];
      float y1 = acc[c][1][r] + bqa[r];
      sv[r] = y0 + y1;
      qv[r] = y0*y0 + y1*y1;
      mv[r] = fmaxf(y0, y1);
    }
    float S = hred4_sum(sv, l);
    float Q = hred4_sum(qv, l);
    float Mx = hred4_max(mv, l);
    if ((l & 3) == 0){
      int ch = c*16 + quad*4 + ((l>>3)&1)*2 + ((l>>2)&1);
      sred[w][ch] = S;
      sred[w][128 + ch] = Q;
      ymax[(size_t)g*128 + ch] = Mx;
    }
  }
  __syncthreads();
  {
    float tot = sred[0][t]+sred[1][t]+sred[2][t]+sred[3][t];
    unsafeAtomicAdd(&stats[256 + t], tot);
  }
}

__global__ void bnparam_kernel(const float* __restrict__ stats, const float* __restrict__ g,
                               const float* __restrict__ bt, float* __restrict__ outAS,
                               int sOff, int qOff, int C){
  int c = threadIdx.x;
  if (c >= C) return;
  const float inv = 1.f/(float)M_;
  float mean = stats[sOff + c] * inv;
  float var  = stats[qOff + c] * inv - mean*mean;
  float a = g[c] * rsqrtf(var + EPS_);
  outAS[c] = a;
  outAS[C + c] = bt[c] - mean*a;
}

__global__ void final_kernel(const float* __restrict__ ymax,
                             const float* __restrict__ stats, float* __restrict__ out){
  int t = blockIdx.x*256 + threadIdx.x;     // (b*S+s)*128 + o
  int o = t & 127;
  float a = stats[768 + o], s = stats[896 + o];
  // g=ones => a = rsqrt(var+eps) > 0, so max commutes with the affine+relu
  out[OUT_FEAT + t] = fmaxf(0.f, a*ymax[t] + s);
}

extern "C" void kernel_launch(void* const* d_in, const int* in_sizes, int n_in,
                              void* d_out, int out_size, void* d_ws, size_t ws_size,
                              hipStream_t stream) {
  const float* xyz = (const float*)d_in[0];
  const float* nrm = (const float*)d_in[1];
  const float* pts = (const float*)d_in[2];
  const int*   fps = (const int*)d_in[3];
  const float* w0  = (const float*)d_in[4];
  const float* b0  = (const float*)d_in[5];
  const float* g0  = (const float*)d_in[6];
  const float* bt0 = (const float*)d_in[7];
  const float* w1  = (const float*)d_in[8];
  const float* b1  = (const float*)d_in[9];
  const float* g1  = (const float*)d_in[10];
  const float* bt1 = (const float*)d_in[11];
  const float* w2  = (const float*)d_in[12];
  const float* b2  = (const float*)d_in[13];
  const float* g2  = (const float*)d_in[14];
  const float* bt2 = (const float*)d_in[15];
  float* out = (float*)d_out;

  char* ws = (char*)d_ws;
  float* stats = (float*)ws;                                  // 4 KB
  int*   idxb  = (int*)(ws + 4096);                           // 2 MB
  float* ymax  = (float*)(ws + 2101248);                      // 8 MB
  float4* packed = (float4*)(ws + 10489856);                  // 1 MB
  unsigned short* wpack = (unsigned short*)(ws + 11538432);   // 32 KB
  unsigned short* Y1 = (unsigned short*)(ws + 18878464);      // 64 MB
  unsigned short* Y2 = (unsigned short*)(ws + 85987328);      // 64 MB (ends 153096192)

  zero_stats_kernel<<<2, 256, 0, stream>>>(stats);
  meta_kernel<<<64, 256, 0, stream>>>(xyz, nrm, fps, out);
  prepack_kernel<<<256, 256, 0, stream>>>(xyz, packed);
  packw_kernel<<<64, 256, 0, stream>>>(w0, w1, w2, wpack);
  knn_kernel<<<4096, 256, 0, stream>>>(packed, fps, idxb);
  conv1_mfma<<<4096, 256, 0, stream>>>(pts, idxb, wpack, b0, Y1, stats);
  bnparam_kernel<<<1, 64, 0, stream>>>(stats, g0, bt0, stats + 512, 0, 64, 64);
  conv2_mfma<<<4096, 256, 0, stream>>>(Y1, wpack + 4096, b1, stats + 512, Y2, stats);
  bnparam_kernel<<<1, 64, 0, stream>>>(stats, g1, bt1, stats + 640, 128, 192, 64);
  conv3_mfma<<<4096, 256, 0, stream>>>(Y2, wpack + 8192, b2, stats + 640, ymax, stats);
  bnparam_kernel<<<1, 128, 0, stream>>>(stats, g2, bt2, stats + 768, 256, 384, 128);
  final_kernel<<<8192, 256, 0, stream>>>(ymax, stats, out);
}

// Round 5
// 300.433 us; speedup vs baseline: 3.5319x; 1.7532x over previous
//
#include <hip/hip_runtime.h>
#include <hip/hip_bf16.h>

#define B_ 16
#define N_ 4096
#define S_ 1024
#define K_ 32
#define D_ 64
#define M_ (B_*S_*K_)            // 524288 rows
#define EPS_ 1e-5f

#define OUT_NRM  (B_*S_*3)       // 49152
#define OUT_FEAT (2*B_*S_*3)     // 98304
#define OUT_FPS  (OUT_FEAT + B_*S_*128)  // 2195456

typedef __attribute__((ext_vector_type(8))) short bf16x8;
typedef __attribute__((ext_vector_type(4))) float f32x4;

__device__ __forceinline__ unsigned short rnb(float x){
  return (unsigned short)((__float_as_uint(x) + 0x8000u) >> 16);
}
__device__ __forceinline__ void split1(float x, short& h, short& l){
  unsigned ux = __float_as_uint(x);
  unsigned uh = (ux + 0x8000u) & 0xFFFF0000u;
  h = (short)(uh >> 16);
  float lo = x - __uint_as_float(uh);
  l = (short)((__float_as_uint(lo) + 0x8000u) >> 16);
}

// reduce 4 values across 16 lr-lanes; lane with bits(3,2)=(b3,b2) holds total of v[2*b3+b2]
__device__ __forceinline__ float hred4_sum(const float v[4], int l){
  bool hi8 = (l & 8) != 0;
  float send0 = hi8 ? v[0] : v[2];
  float send1 = hi8 ? v[1] : v[3];
  float r0 = __shfl_xor(send0, 8);
  float r1 = __shfl_xor(send1, 8);
  float a0 = (hi8 ? v[2] : v[0]) + r0;
  float a1 = (hi8 ? v[3] : v[1]) + r1;
  bool hi4 = (l & 4) != 0;
  float send = hi4 ? a0 : a1;
  float r = __shfl_xor(send, 4);
  float a = (hi4 ? a1 : a0) + r;
  a += __shfl_xor(a, 2);
  a += __shfl_xor(a, 1);
  return a;
}
__device__ __forceinline__ float hred4_max(const float v[4], int l){
  bool hi8 = (l & 8) != 0;
  float send0 = hi8 ? v[0] : v[2];
  float send1 = hi8 ? v[1] : v[3];
  float r0 = __shfl_xor(send0, 8);
  float r1 = __shfl_xor(send1, 8);
  float a0 = fmaxf(hi8 ? v[2] : v[0], r0);
  float a1 = fmaxf(hi8 ? v[3] : v[1], r1);
  bool hi4 = (l & 4) != 0;
  float send = hi4 ? a0 : a1;
  float r = __shfl_xor(send, 4);
  float a = fmaxf(hi4 ? a1 : a0, r);
  a = fmaxf(a, __shfl_xor(a, 2));
  a = fmaxf(a, __shfl_xor(a, 1));
  return a;
}

// stats: 8 replicas x 512 floats (S1@0 Q1@64 S2@128 Q2@192 S3@256(128) Q3@384(128))
__global__ void zero_stats_kernel(float* __restrict__ stats){
  int t = blockIdx.x*256 + threadIdx.x;
  stats[t] = 0.f;    // grid covers 4096 floats
}

__global__ void meta_kernel(const float* __restrict__ xyz, const float* __restrict__ nrm,
                            const int* __restrict__ fps, float* __restrict__ out){
  int t = blockIdx.x*256 + threadIdx.x;
  if (t >= B_*S_) return;
  int b = t >> 10;
  int n = fps[t];
  const float* xp = xyz + ((size_t)b*N_ + n)*3;
  out[t*3+0] = xp[0]; out[t*3+1] = xp[1]; out[t*3+2] = xp[2];
  const float* pp = nrm + ((size_t)b*N_ + n)*3;
  out[OUT_NRM + t*3+0] = pp[0]; out[OUT_NRM + t*3+1] = pp[1]; out[OUT_NRM + t*3+2] = pp[2];
  out[OUT_FPS + t] = (float)n;
}

__global__ void prepack_kernel(const float* __restrict__ xyz, float4* __restrict__ packed){
  int t = blockIdx.x*256 + threadIdx.x;
  if (t >= B_*N_) return;
  float x = xyz[t*3+0], y = xyz[t*3+1], z = xyz[t*3+2];
  float pp = __fadd_rn(__fadd_rn(__fmul_rn(x,x), __fmul_rn(y,y)), __fmul_rn(z,z));
  packed[t] = make_float4(x, y, z, pp);
}

// pack W into per-lane MFMA A-fragments (bf16). w0 [0,4096) w1 [4096,8192) w2 [8192,16384)
__global__ void packw_kernel(const float* __restrict__ w0, const float* __restrict__ w1,
                             const float* __restrict__ w2, unsigned short* __restrict__ dst){
  int e = blockIdx.x*256 + threadIdx.x;
  if (e >= 16384) return;
  const float* W; int base;
  if (e < 4096){ W = w0; base = 0; }
  else if (e < 8192){ W = w1; base = 4096; }
  else { W = w2; base = 8192; }
  int r = e - base;
  int frag = r >> 9;          // (cht*2 + ks)
  int lane = (r >> 3) & 63;
  int j = r & 7;
  int cht = frag >> 1, ks = frag & 1;
  int m = lane & 15, quad = lane >> 4;
  int ch = cht*16 + m, k = ks*32 + quad*8 + j;
  dst[e] = rnb(W[ch*64 + k]);
}

// ---------------- KNN (unchanged) ----------------
__global__ __launch_bounds__(256, 3) void knn_kernel(const float4* __restrict__ packed,
                                                     const int* __restrict__ fps,
                                                     int* __restrict__ idxout){
  __shared__ unsigned skey[4][64];
  __shared__ int      sidx[4][64];
  const int w = threadIdx.x >> 6;
  const int l = threadIdx.x & 63;
  const int q = blockIdx.x*4 + w;
  const int b = q >> 10;
  const float4* pb = packed + (size_t)b*N_;
  const int nq = fps[q];
  const float4 qp = pb[nq];
  const float qx = qp.x, qy = qp.y, qz = qp.z, qq = qp.w;

  unsigned key[64];
  unsigned minkey = 0xFFFFFFFFu;
  #pragma unroll
  for (int i = 0; i < 64; i++){
    float4 p = pb[i*64 + l];
    float dt = __fadd_rn(__fadd_rn(__fmul_rn(qx,p.x), __fmul_rn(qy,p.y)), __fmul_rn(qz,p.z));
    float d  = __fsub_rn(__fadd_rn(qq,p.w), __fmul_rn(2.f,dt));
    unsigned u = __float_as_uint(d);
    u ^= (unsigned)(((int)u >> 31)) | 0x80000000u;
    key[i] = u;
    minkey = min(minkey, u);
  }
  {
    unsigned v = minkey;
    #pragma unroll
    for (int k = 2; k <= 64; k <<= 1){
      #pragma unroll
      for (int j = k >> 1; j > 0; j >>= 1){
        unsigned o = (unsigned)__shfl_xor((int)v, j);
        bool keepmin = (((l & k) == 0)) ^ ((l & j) != 0);
        unsigned mn = min(v, o), mx = max(v, o);
        v = keepmin ? mn : mx;
      }
    }
    minkey = v;
  }
  const unsigned T = (unsigned)__shfl((int)minkey, 31);

  int c = 0;
  #pragma unroll
  for (int i = 0; i < 64; i++) c += (key[i] <= T) ? 1 : 0;
  int inc = c;
  #pragma unroll
  for (int off = 1; off < 64; off <<= 1){
    int t2 = __shfl_up(inc, off);
    if (l >= off) inc += t2;
  }
  const int excl = inc - c;
  const int total = __shfl(inc, 63);

  const size_t obase = (size_t)q * K_;
  if (total <= 64){
    int off = excl;
    #pragma unroll
    for (int i = 0; i < 64; i++){
      if (key[i] <= T){
        skey[w][off] = key[i];
        sidx[w][off] = i*64 + l;
        off++;
      }
    }
    unsigned mykey = 0xFFFFFFFFu, myidx = 0xFFFFFFFFu;
    if (l < total){ mykey = skey[w][l]; myidx = (unsigned)sidx[w][l]; }
    unsigned long long sk = ((unsigned long long)mykey << 32) | (unsigned long long)myidx;
    #pragma unroll
    for (int k = 2; k <= 64; k <<= 1){
      #pragma unroll
      for (int j = k >> 1; j > 0; j >>= 1){
        unsigned long long o = __shfl_xor(sk, j);
        bool keepmin = (((l & k) == 0)) ^ ((l & j) != 0);
        unsigned long long mn = (sk < o) ? sk : o;
        unsigned long long mx = (sk < o) ? o : sk;
        sk = keepmin ? mn : mx;
      }
    }
    if (l < 32) idxout[obase + l] = (int)(unsigned)(sk & 0xFFFFFFFFull);
  } else {
    unsigned long long lo = 0, hi = (1ull << 44) - 1;
    for (int it = 0; it < 44; ++it){
      unsigned long long mid = (lo + hi) >> 1;
      unsigned midk = (unsigned)(mid >> 12);
      unsigned midi = (unsigned)(mid & 0xFFFull);
      int cc = 0;
      #pragma unroll
      for (int i = 0; i < 64; i++){
        unsigned n = (unsigned)(i*64 + l);
        cc += (key[i] < midk || (key[i] == midk && n <= midi)) ? 1 : 0;
      }
      #pragma unroll
      for (int o2 = 32; o2 > 0; o2 >>= 1) cc += __shfl_xor(cc, o2);
      if (cc >= 32) hi = mid; else lo = mid + 1;
    }
    const unsigned Ck = (unsigned)(lo >> 12);
    const unsigned Ci = (unsigned)(lo & 0xFFFull);
    int c2 = 0;
    #pragma unroll
    for (int i = 0; i < 64; i++){
      unsigned n = (unsigned)(i*64 + l);
      c2 += (key[i] < Ck || (key[i] == Ck && n <= Ci)) ? 1 : 0;
    }
    int inc2 = c2;
    #pragma unroll
    for (int off = 1; off < 64; off <<= 1){
      int t2 = __shfl_up(inc2, off);
      if (l >= off) inc2 += t2;
    }
    int off3 = inc2 - c2;
    #pragma unroll
    for (int i = 0; i < 64; i++){
      unsigned n = (unsigned)(i*64 + l);
      if (key[i] < Ck || (key[i] == Ck && n <= Ci)){
        sidx[w][off3] = i*64 + l;
        off3++;
      }
    }
    if (l < 32) idxout[obase + l] = sidx[w][l];
  }
}

// ---- conv1: gather -> split-MFMA -> Y1 + stats. 64 rows/wave, grid 2048 ----
__global__ __launch_bounds__(256, 2) void conv1_mfma(const float* __restrict__ pts,
    const int* __restrict__ idx, const unsigned short* __restrict__ wpk,
    const float* __restrict__ bias, unsigned short* __restrict__ Yo,
    float* __restrict__ stats){
  __shared__ float sred[4][128];
  const int t = threadIdx.x, w = t>>6, l = t&63, quad = l>>4, lr = l&15;
  const int m0 = blockIdx.x*256;
  const int Rw = m0 + w*64;
  const int b = m0 >> 15;
  bf16x8 wf[4][2];
  #pragma unroll
  for (int c = 0; c < 4; c++)
    #pragma unroll
    for (int s = 0; s < 2; s++)
      wf[c][s] = *(const bf16x8*)(wpk + (((c*2+s)<<6) + l)*8);
  f32x4 acc[4][4];
  #pragma unroll
  for (int c = 0; c < 4; c++)
    #pragma unroll
    for (int rt = 0; rt < 4; rt++)
      acc[c][rt] = (f32x4){0.f,0.f,0.f,0.f};
  int ri[4];
  #pragma unroll
  for (int rt = 0; rt < 4; rt++) ri[rt] = idx[Rw + rt*16 + lr];
  #pragma unroll
  for (int s = 0; s < 2; s++){
    #pragma unroll
    for (int rt = 0; rt < 4; rt++){
      const float* pr = pts + ((size_t)(b*4096 + ri[rt]))*64;
      float4 v0 = *(const float4*)(pr + s*32 + quad*8);
      float4 v1 = *(const float4*)(pr + s*32 + quad*8 + 4);
      float xs[8] = {v0.x,v0.y,v0.z,v0.w,v1.x,v1.y,v1.z,v1.w};
      bf16x8 xh, xl;
      #pragma unroll
      for (int j = 0; j < 8; j++){ short hh, ll; split1(xs[j], hh, ll); xh[j]=hh; xl[j]=ll; }
      #pragma unroll
      for (int c = 0; c < 4; c++){
        acc[c][rt] = __builtin_amdgcn_mfma_f32_16x16x32_bf16(wf[c][s], xh, acc[c][rt], 0,0,0);
        acc[c][rt] = __builtin_amdgcn_mfma_f32_16x16x32_bf16(wf[c][s], xl, acc[c][rt], 0,0,0);
      }
    }
  }
  const int rtg0 = Rw >> 4;
  #pragma unroll
  for (int c = 0; c < 4; c++){
    float4 bq = *(const float4*)(bias + c*16 + quad*4);
    float bqa[4] = {bq.x, bq.y, bq.z, bq.w};
    float sv[4] = {0,0,0,0}, qv[4] = {0,0,0,0};
    int kb = c*2 + (quad>>1);
    int sub = (quad&1)*4;
    #pragma unroll
    for (int rt = 0; rt < 4; rt++){
      float y[4];
      #pragma unroll
      for (int r = 0; r < 4; r++){
        y[r] = acc[c][rt][r] + bqa[r];
        sv[r] += y[r];
        qv[r] += y[r]*y[r];
      }
      uint2 p;
      p.x = (unsigned)rnb(y[0]) | ((unsigned)rnb(y[1])<<16);
      p.y = (unsigned)rnb(y[2]) | ((unsigned)rnb(y[3])<<16);
      *(uint2*)(Yo + ((((rtg0+rt)*8 + kb)*16 + lr)*8 + sub)) = p;
    }
    float S = hred4_sum(sv, l);
    float Q = hred4_sum(qv, l);
    if ((l & 3) == 0){
      int ch = c*16 + quad*4 + ((l>>3)&1)*2 + ((l>>2)&1);
      sred[w][ch] = S;
      sred[w][64 + ch] = Q;
    }
  }
  __syncthreads();
  if (t < 128){
    float tot = sred[0][t]+sred[1][t]+sred[2][t]+sred[3][t];
    unsafeAtomicAdd(&stats[(blockIdx.x & 7)*512 + t], tot);
  }
}

// ---- conv2: Y1 -> affine+relu -> MFMA (no split) -> Y2 + stats. 64 rows/wave ----
__global__ __launch_bounds__(256, 2) void conv2_mfma(const unsigned short* __restrict__ Yi,
    const unsigned short* __restrict__ wpk, const float* __restrict__ bias,
    const float* __restrict__ aff, unsigned short* __restrict__ Yo,
    float* __restrict__ stats){
  __shared__ float sred[4][128];
  const int t = threadIdx.x, w = t>>6, l = t&63, quad = l>>4, lr = l&15;
  const int m0 = blockIdx.x*256;
  const int Rw = m0 + w*64;
  bf16x8 wf[4][2];
  #pragma unroll
  for (int c = 0; c < 4; c++)
    #pragma unroll
    for (int s = 0; s < 2; s++)
      wf[c][s] = *(const bf16x8*)(wpk + (((c*2+s)<<6) + l)*8);
  f32x4 acc[4][4];
  #pragma unroll
  for (int c = 0; c < 4; c++)
    #pragma unroll
    for (int rt = 0; rt < 4; rt++)
      acc[c][rt] = (f32x4){0.f,0.f,0.f,0.f};
  const int rtg0 = Rw >> 4;
  #pragma unroll
  for (int s = 0; s < 2; s++){
    float4 A0 = *(const float4*)(aff + s*32 + quad*8);
    float4 A1 = *(const float4*)(aff + s*32 + quad*8 + 4);
    float4 B0 = *(const float4*)(aff + 64 + s*32 + quad*8);
    float4 B1 = *(const float4*)(aff + 64 + s*32 + quad*8 + 4);
    float aA[8] = {A0.x,A0.y,A0.z,A0.w,A1.x,A1.y,A1.z,A1.w};
    float aB[8] = {B0.x,B0.y,B0.z,B0.w,B1.x,B1.y,B1.z,B1.w};
    #pragma unroll
    for (int rt = 0; rt < 4; rt++){
      uint4 u = *(const uint4*)(Yi + (((rtg0+rt)*8 + s*4 + quad)*16 + lr)*8);
      unsigned ua[4] = {u.x,u.y,u.z,u.w};
      bf16x8 xb;
      #pragma unroll
      for (int j = 0; j < 8; j++){
        unsigned wd = ua[j>>1];
        float yf = __uint_as_float((j&1) ? (wd & 0xFFFF0000u) : (wd << 16));
        float x = fmaxf(0.f, fmaf(yf, aA[j], aB[j]));
        xb[j] = (short)rnb(x);
      }
      #pragma unroll
      for (int c = 0; c < 4; c++)
        acc[c][rt] = __builtin_amdgcn_mfma_f32_16x16x32_bf16(wf[c][s], xb, acc[c][rt], 0,0,0);
    }
  }
  #pragma unroll
  for (int c = 0; c < 4; c++){
    float4 bq = *(const float4*)(bias + c*16 + quad*4);
    float bqa[4] = {bq.x, bq.y, bq.z, bq.w};
    float sv[4] = {0,0,0,0}, qv[4] = {0,0,0,0};
    int kb = c*2 + (quad>>1);
    int sub = (quad&1)*4;
    #pragma unroll
    for (int rt = 0; rt < 4; rt++){
      float y[4];
      #pragma unroll
      for (int r = 0; r < 4; r++){
        y[r] = acc[c][rt][r] + bqa[r];
        sv[r] += y[r];
        qv[r] += y[r]*y[r];
      }
      uint2 p;
      p.x = (unsigned)rnb(y[0]) | ((unsigned)rnb(y[1])<<16);
      p.y = (unsigned)rnb(y[2]) | ((unsigned)rnb(y[3])<<16);
      *(uint2*)(Yo + ((((rtg0+rt)*8 + kb)*16 + lr)*8 + sub)) = p;
    }
    float S = hred4_sum(sv, l);
    float Q = hred4_sum(qv, l);
    if ((l & 3) == 0){
      int ch = c*16 + quad*4 + ((l>>3)&1)*2 + ((l>>2)&1);
      sred[w][ch] = S;
      sred[w][64 + ch] = Q;
    }
  }
  __syncthreads();
  if (t < 128){
    float tot = sred[0][t]+sred[1][t]+sred[2][t]+sred[3][t];
    unsafeAtomicAdd(&stats[(blockIdx.x & 7)*512 + 128 + t], tot);
  }
}

// ---- conv3: Y2 -> affine+relu -> MFMA (no split) -> K-maxpool + stats. 32 rows/wave ----
__global__ __launch_bounds__(256, 2) void conv3_mfma(const unsigned short* __restrict__ Yi,
    const unsigned short* __restrict__ wpk, const float* __restrict__ bias,
    const float* __restrict__ aff, float* __restrict__ ymax,
    float* __restrict__ stats){
  __shared__ float sred[4][256];
  const int t = threadIdx.x, w = t>>6, l = t&63, quad = l>>4, lr = l&15;
  const int m0 = blockIdx.x*128;
  const int Rw = m0 + w*32;
  bf16x8 wf[8][2];
  #pragma unroll
  for (int c = 0; c < 8; c++)
    #pragma unroll
    for (int s = 0; s < 2; s++)
      wf[c][s] = *(const bf16x8*)(wpk + (((c*2+s)<<6) + l)*8);
  f32x4 acc[8][2];
  #pragma unroll
  for (int c = 0; c < 8; c++){
    acc[c][0] = (f32x4){0.f,0.f,0.f,0.f};
    acc[c][1] = (f32x4){0.f,0.f,0.f,0.f};
  }
  const int rtg0 = Rw >> 4;
  #pragma unroll
  for (int s = 0; s < 2; s++){
    float4 A0 = *(const float4*)(aff + s*32 + quad*8);
    float4 A1 = *(const float4*)(aff + s*32 + quad*8 + 4);
    float4 B0 = *(const float4*)(aff + 64 + s*32 + quad*8);
    float4 B1 = *(const float4*)(aff + 64 + s*32 + quad*8 + 4);
    float aA[8] = {A0.x,A0.y,A0.z,A0.w,A1.x,A1.y,A1.z,A1.w};
    float aB[8] = {B0.x,B0.y,B0.z,B0.w,B1.x,B1.y,B1.z,B1.w};
    #pragma unroll
    for (int rt = 0; rt < 2; rt++){
      uint4 u = *(const uint4*)(Yi + (((rtg0+rt)*8 + s*4 + quad)*16 + lr)*8);
      unsigned ua[4] = {u.x,u.y,u.z,u.w};
      bf16x8 xb;
      #pragma unroll
      for (int j = 0; j < 8; j++){
        unsigned wd = ua[j>>1];
        float yf = __uint_as_float((j&1) ? (wd & 0xFFFF0000u) : (wd << 16));
        float x = fmaxf(0.f, fmaf(yf, aA[j], aB[j]));
        xb[j] = (short)rnb(x);
      }
      #pragma unroll
      for (int c = 0; c < 8; c++)
        acc[c][rt] = __builtin_amdgcn_mfma_f32_16x16x32_bf16(wf[c][s], xb, acc[c][rt], 0,0,0);
    }
  }
  const int g = Rw >> 5;       // group = b*S + s (wave = one K=32 group)
  #pragma unroll
  for (int c = 0; c < 8; c++){
    float4 bq = *(const float4*)(bias + c*16 + quad*4);
    float bqa[4] = {bq.x, bq.y, bq.z, bq.w};
    float sv[4], qv[4], mv[4];
    #pragma unroll
    for (int r = 0; r < 4; r++){
      float y0 = acc[c][0][r] + bqa[r];
      float y1 = acc[c][1][r] + bqa[r];
      sv[r] = y0 + y1;
      qv[r] = y0*y0 + y1*y1;
      mv[r] = fmaxf(y0, y1);
    }
    float S = hred4_sum(sv, l);
    float Q = hred4_sum(qv, l);
    float Mx = hred4_max(mv, l);
    if ((l & 3) == 0){
      int ch = c*16 + quad*4 + ((l>>3)&1)*2 + ((l>>2)&1);
      sred[w][ch] = S;
      sred[w][128 + ch] = Q;
      ymax[(size_t)g*128 + ch] = Mx;
    }
  }
  __syncthreads();
  {
    float tot = sred[0][t]+sred[1][t]+sred[2][t]+sred[3][t];
    unsafeAtomicAdd(&stats[(blockIdx.x & 7)*512 + 256 + t], tot);
  }
}

__global__ void bnparam_kernel(const float* __restrict__ stats, const float* __restrict__ g,
                               const float* __restrict__ bt, float* __restrict__ outAS,
                               int sOff, int qOff, int C){
  int c = threadIdx.x;
  if (c >= C) return;
  const float inv = 1.f/(float)M_;
  float S = 0.f, Q = 0.f;
  #pragma unroll
  for (int r = 0; r < 8; r++){
    S += stats[r*512 + sOff + c];
    Q += stats[r*512 + qOff + c];
  }
  float mean = S * inv;
  float var  = Q * inv - mean*mean;
  float a = g[c] * rsqrtf(var + EPS_);
  outAS[c] = a;
  outAS[C + c] = bt[c] - mean*a;
}

__global__ void final_kernel(const float* __restrict__ ymax,
                             const float* __restrict__ affb, float* __restrict__ out){
  int t = blockIdx.x*256 + threadIdx.x;     // (b*S+s)*128 + o
  int o = t & 127;
  float a = affb[256 + o], s = affb[384 + o];
  // g=ones => a = rsqrt(var+eps) > 0, so max commutes with the affine+relu
  out[OUT_FEAT + t] = fmaxf(0.f, a*ymax[t] + s);
}

extern "C" void kernel_launch(void* const* d_in, const int* in_sizes, int n_in,
                              void* d_out, int out_size, void* d_ws, size_t ws_size,
                              hipStream_t stream) {
  const float* xyz = (const float*)d_in[0];
  const float* nrm = (const float*)d_in[1];
  const float* pts = (const float*)d_in[2];
  const int*   fps = (const int*)d_in[3];
  const float* w0  = (const float*)d_in[4];
  const float* b0  = (const float*)d_in[5];
  const float* g0  = (const float*)d_in[6];
  const float* bt0 = (const float*)d_in[7];
  const float* w1  = (const float*)d_in[8];
  const float* b1  = (const float*)d_in[9];
  const float* g1  = (const float*)d_in[10];
  const float* bt1 = (const float*)d_in[11];
  const float* w2  = (const float*)d_in[12];
  const float* b2  = (const float*)d_in[13];
  const float* g2  = (const float*)d_in[14];
  const float* bt2 = (const float*)d_in[15];
  float* out = (float*)d_out;

  char* ws = (char*)d_ws;
  float* stats = (float*)ws;                                  // 16 KB (8 replicas x 512 f)
  float* affb  = (float*)(ws + 16384);                        // 2 KB aff params
  int*   idxb  = (int*)(ws + 20480);                          // 2 MB
  float* ymax  = (float*)(ws + 2117632);                      // 8 MB
  float4* packed = (float4*)(ws + 10506240);                  // 1 MB
  unsigned short* wpack = (unsigned short*)(ws + 11554816);   // 32 KB
  unsigned short* Y1 = (unsigned short*)(ws + 18878464);      // 64 MB
  unsigned short* Y2 = (unsigned short*)(ws + 85987328);      // 64 MB (ends 153096192)

  zero_stats_kernel<<<16, 256, 0, stream>>>(stats);
  meta_kernel<<<64, 256, 0, stream>>>(xyz, nrm, fps, out);
  prepack_kernel<<<256, 256, 0, stream>>>(xyz, packed);
  packw_kernel<<<64, 256, 0, stream>>>(w0, w1, w2, wpack);
  knn_kernel<<<4096, 256, 0, stream>>>(packed, fps, idxb);
  conv1_mfma<<<2048, 256, 0, stream>>>(pts, idxb, wpack, b0, Y1, stats);
  bnparam_kernel<<<1, 64, 0, stream>>>(stats, g0, bt0, affb, 0, 64, 64);
  conv2_mfma<<<2048, 256, 0, stream>>>(Y1, wpack + 4096, b1, affb, Y2, stats);
  bnparam_kernel<<<1, 64, 0, stream>>>(stats, g1, bt1, affb + 128, 128, 192, 64);
  conv3_mfma<<<4096, 256, 0, stream>>>(Y2, wpack + 8192, b2, affb + 128, ymax, stats);
  bnparam_kernel<<<1, 128, 0, stream>>>(stats, g2, bt2, affb + 256, 256, 384, 128);
  final_kernel<<<8192, 256, 0, stream>>>(ymax, affb, out);
}